// Round 1
// baseline (386.622 us; speedup 1.0000x reference)
//
#include <hip/hip_runtime.h>
#include <hip/hip_bf16.h>

#define NN   20000
#define NE   320000
#define KSEL 4096

typedef short bf16x8 __attribute__((ext_vector_type(8)));
typedef float f32x4  __attribute__((ext_vector_type(4)));

static __device__ __forceinline__ float bf2f(unsigned short u){
  return __uint_as_float(((unsigned int)u) << 16);
}
static __device__ __forceinline__ unsigned short f2bf(float f){
  unsigned int x = __float_as_uint(f);
  x += 0x7fffu + ((x >> 16) & 1u);   // round-to-nearest-even
  return (unsigned short)(x >> 16);
}

// ---------------- conversions ----------------
__global__ void k_cvt_x(const float* __restrict__ X, unsigned short* __restrict__ Xb){
  int i = (blockIdx.x * 256 + threadIdx.x) * 4;   // exact: 5000*256*4 = 20000*256
  float4 v = *(const float4*)(X + i);
  ushort4 o = { f2bf(v.x), f2bf(v.y), f2bf(v.z), f2bf(v.w) };
  *(ushort4*)(Xb + i) = o;
}

// Wt layout: rows [0,256)=W1^T, [256,512)=Wsd^T, [512,768)=W2^T; each row k-contiguous.
__global__ void k_cvt_w(const float* __restrict__ W1, const float* __restrict__ Wsd,
                        const float* __restrict__ W2, unsigned short* __restrict__ Wt){
  int t = blockIdx.x * 256 + threadIdx.x;  // 0 .. 3*65536-1
  int w = t >> 16;
  int o = (t >> 8) & 255;
  int k = t & 255;
  const float* W = (w == 0) ? W1 : (w == 1 ? Wsd : W2);
  Wt[t] = f2bf(W[k * 256 + o]);
}

// ---------------- idx = nonzero(labels==1) (stable order via block scan) ----------------
__global__ __launch_bounds__(1024) void k_idx_scan(const int* __restrict__ labels,
                                                   int* __restrict__ idx){
  __shared__ int sh[1024];
  __shared__ int carry_s;
  int tid = threadIdx.x;
  if (tid == 0) carry_s = 0;
  __syncthreads();
  for (int base = 0; base < NN; base += 1024){
    int n = base + tid;
    int v = (n < NN && labels[n] == 1) ? 1 : 0;
    int acc = v;
    sh[tid] = acc; __syncthreads();
    for (int off = 1; off < 1024; off <<= 1){
      int t = (tid >= off) ? sh[tid - off] : 0;
      __syncthreads();
      acc += t; sh[tid] = acc; __syncthreads();
    }
    int c = carry_s;
    if (v){ int p = c + acc - 1; if (p < KSEL) idx[p] = n; }
    __syncthreads();
    if (tid == 1023) carry_s = c + acc;
    __syncthreads();
  }
}

// ---------------- CSR build ----------------
__global__ void k_hist(const int* __restrict__ row, int* __restrict__ counts){
  int e = blockIdx.x * 256 + threadIdx.x;
  if (e < NE) atomicAdd(&counts[row[e]], 1);
}

__global__ __launch_bounds__(1024) void k_row_scan(const int* __restrict__ counts,
                                                   int* __restrict__ start,
                                                   int* __restrict__ cursor){
  __shared__ int sh[1024];
  __shared__ int carry_s;
  int tid = threadIdx.x;
  if (tid == 0) carry_s = 0;
  __syncthreads();
  for (int base = 0; base < NN; base += 1024){
    int n = base + tid;
    int v = (n < NN) ? counts[n] : 0;
    int acc = v;
    sh[tid] = acc; __syncthreads();
    for (int off = 1; off < 1024; off <<= 1){
      int t = (tid >= off) ? sh[tid - off] : 0;
      __syncthreads();
      acc += t; sh[tid] = acc; __syncthreads();
    }
    int c = carry_s;
    if (n < NN){ start[n] = c + acc - v; cursor[n] = c + acc - v; }
    __syncthreads();
    if (tid == 1023) carry_s = c + acc;
    __syncthreads();
  }
  if (tid == 0) start[NN] = carry_s;
}

__global__ void k_scatter(const int* __restrict__ row, int* __restrict__ cursor,
                          int* __restrict__ perm){
  int e = blockIdx.x * 256 + threadIdx.x;
  if (e < NE){
    int r = row[e];
    int p = atomicAdd(&cursor[r], 1);
    perm[p] = e;
  }
}

// ---------------- bf16 MFMA GEMM: out[M,ldo] tile = A[M,256] @ Wt^T (Wt is [O][256] o-major) ----
// block: 256 thr (4 waves), tile 128(M) x 64(O), K=256 full.
__global__ __launch_bounds__(256) void k_gemm(const unsigned short* __restrict__ A,
                                              const unsigned short* __restrict__ Wt,
                                              unsigned short* __restrict__ out,
                                              int M, int ldo){
  __shared__ unsigned short lds[64 * 264];   // 64 o-rows, 256 k + 8 pad
  int tid = threadIdx.x;
  int wave = tid >> 6, lane = tid & 63;
  int lm = lane & 15, lq = lane >> 4;
  int mBase = blockIdx.x * 128;
  int oBase = blockIdx.y * 64;
  #pragma unroll
  for (int it = 0; it < 8; ++it){
    int c = it * 256 + tid;            // 2048 chunks of 8 bf16
    int o = c >> 5, kk = (c & 31) << 3;
    *(bf16x8*)&lds[o * 264 + kk] = *(const bf16x8*)&Wt[(oBase + o) * 256 + kk];
  }
  __syncthreads();
  f32x4 acc[2][4] = {};
  int r0 = mBase + wave * 32 + lm;
  int r1 = r0 + 16;
  #pragma unroll
  for (int ks = 0; ks < 256; ks += 32){
    int ka = ks + lq * 8;
    bf16x8 a0 = {0,0,0,0,0,0,0,0}, a1 = {0,0,0,0,0,0,0,0};
    if (r0 < M) a0 = *(const bf16x8*)&A[(size_t)r0 * 256 + ka];
    if (r1 < M) a1 = *(const bf16x8*)&A[(size_t)r1 * 256 + ka];
    #pragma unroll
    for (int os = 0; os < 4; ++os){
      bf16x8 b = *(const bf16x8*)&lds[(os * 16 + lm) * 264 + ka];
      acc[0][os] = __builtin_amdgcn_mfma_f32_16x16x32_bf16(a0, b, acc[0][os], 0, 0, 0);
      acc[1][os] = __builtin_amdgcn_mfma_f32_16x16x32_bf16(a1, b, acc[1][os], 0, 0, 0);
    }
  }
  #pragma unroll
  for (int ms = 0; ms < 2; ++ms){
    int rb = mBase + wave * 32 + ms * 16 + lq * 4;
    #pragma unroll
    for (int os = 0; os < 4; ++os){
      int col = oBase + os * 16 + lm;
      #pragma unroll
      for (int r = 0; r < 4; ++r){
        int row = rb + r;
        if (row < M) out[(size_t)row * ldo + col] = f2bf(acc[ms][os][r]);
      }
    }
  }
}

// ---------------- s @ s^T : [4096,256] bf16 -> [4096,4096] f32 ----------------
// block 256 thr (4 waves), tile 128x128; frags straight from global (S is 2MB, L2-resident).
__global__ __launch_bounds__(256) void k_gemm_st(const unsigned short* __restrict__ S,
                                                 float* __restrict__ out1){
  int tid = threadIdx.x, wave = tid >> 6, lane = tid & 63;
  int lm = lane & 15, lq = lane >> 4;
  int mBase = blockIdx.x * 128 + wave * 32;
  int oBase = blockIdx.y * 128;
  f32x4 acc[2][8] = {};
  #pragma unroll
  for (int ks = 0; ks < 256; ks += 32){
    int ka = ks + lq * 8;
    bf16x8 a0 = *(const bf16x8*)&S[(size_t)(mBase + lm) * 256 + ka];
    bf16x8 a1 = *(const bf16x8*)&S[(size_t)(mBase + 16 + lm) * 256 + ka];
    #pragma unroll
    for (int os = 0; os < 8; ++os){
      bf16x8 b = *(const bf16x8*)&S[(size_t)(oBase + os * 16 + lm) * 256 + ka];
      acc[0][os] = __builtin_amdgcn_mfma_f32_16x16x32_bf16(a0, b, acc[0][os], 0, 0, 0);
      acc[1][os] = __builtin_amdgcn_mfma_f32_16x16x32_bf16(a1, b, acc[1][os], 0, 0, 0);
    }
  }
  #pragma unroll
  for (int ms = 0; ms < 2; ++ms){
    int rb = mBase + ms * 16 + lq * 4;
    #pragma unroll
    for (int os = 0; os < 8; ++os){
      int col = oBase + os * 16 + lm;
      #pragma unroll
      for (int r = 0; r < 4; ++r)
        out1[(size_t)(rb + r) * 4096 + col] = acc[ms][os][r];
    }
  }
}

// ---------------- SpMM (CSR, one wave per destination row, 4 dims/lane) ----------------
__global__ __launch_bounds__(256) void k_spmm1(const unsigned short* __restrict__ supX,
    const int* __restrict__ start, const int* __restrict__ perm,
    const int* __restrict__ ecol, const float* __restrict__ ew,
    const float* __restrict__ b1, unsigned short* __restrict__ h){
  int wave = threadIdx.x >> 6, lane = threadIdx.x & 63;
  int n = blockIdx.x * 4 + wave;          // 5000*4 = 20000 exact
  int s = start[n], e = start[n + 1];
  int d = lane * 4;
  float a0 = 0, a1 = 0, a2 = 0, a3 = 0;
  for (int j = s; j < e; ++j){
    int eid = perm[j];
    int c = ecol[eid];
    float w = ew[eid];
    ushort4 v = *(const ushort4*)&supX[(size_t)c * 512 + d];
    a0 += w * bf2f(v.x); a1 += w * bf2f(v.y); a2 += w * bf2f(v.z); a3 += w * bf2f(v.w);
  }
  float4 b = *(const float4*)&b1[d];
  ushort4 o = { f2bf(fmaxf(a0 + b.x, 0.f)), f2bf(fmaxf(a1 + b.y, 0.f)),
                f2bf(fmaxf(a2 + b.z, 0.f)), f2bf(fmaxf(a3 + b.w, 0.f)) };
  *(ushort4*)&h[(size_t)n * 256 + d] = o;
}

__global__ __launch_bounds__(256) void k_spmm2(const unsigned short* __restrict__ s2,
    const int* __restrict__ idx, const int* __restrict__ start, const int* __restrict__ perm,
    const int* __restrict__ ecol, const float* __restrict__ ew,
    const float* __restrict__ b2, float* __restrict__ out0){
  int wave = threadIdx.x >> 6, lane = threadIdx.x & 63;
  int i = blockIdx.x * 4 + wave;          // 1024*4 = 4096
  int n = idx[i];
  int s = start[n], e = start[n + 1];
  int d = lane * 4;
  float a0 = 0, a1 = 0, a2 = 0, a3 = 0;
  for (int j = s; j < e; ++j){
    int eid = perm[j];
    int c = ecol[eid];
    float w = ew[eid];
    ushort4 v = *(const ushort4*)&s2[(size_t)c * 256 + d];
    a0 += w * bf2f(v.x); a1 += w * bf2f(v.y); a2 += w * bf2f(v.z); a3 += w * bf2f(v.w);
  }
  float4 b = *(const float4*)&b2[d];
  float4 o = { a0 + b.x, a1 + b.y, a2 + b.z, a3 + b.w };
  *(float4*)&out0[(size_t)i * 256 + d] = o;
}

__global__ __launch_bounds__(256) void k_spmm_sd(const unsigned short* __restrict__ supX,
    const int* __restrict__ idx, const int* __restrict__ start, const int* __restrict__ perm,
    const int* __restrict__ ecol, const float* __restrict__ ew,
    const float* __restrict__ bsd, unsigned short* __restrict__ sel){
  int wave = threadIdx.x >> 6, lane = threadIdx.x & 63;
  int i = blockIdx.x * 4 + wave;
  int n = idx[i];
  int s = start[n], e = start[n + 1];
  int d = lane * 4;
  float a0 = 0, a1 = 0, a2 = 0, a3 = 0;
  for (int j = s; j < e; ++j){
    int eid = perm[j];
    int c = ecol[eid];
    float w = ew[eid];
    ushort4 v = *(const ushort4*)&supX[(size_t)c * 512 + 256 + d];
    a0 += w * bf2f(v.x); a1 += w * bf2f(v.y); a2 += w * bf2f(v.z); a3 += w * bf2f(v.w);
  }
  float4 b = *(const float4*)&bsd[d];
  ushort4 o = { f2bf(a0 + b.x), f2bf(a1 + b.y), f2bf(a2 + b.z), f2bf(a3 + b.w) };
  *(ushort4*)&sel[(size_t)i * 256 + d] = o;
}

extern "C" void kernel_launch(void* const* d_in, const int* in_sizes, int n_in,
                              void* d_out, int out_size, void* d_ws, size_t ws_size,
                              hipStream_t stream){
  const float* X    = (const float*)d_in[0];
  const int*   erow = (const int*)d_in[1];
  const int*   ecol = (const int*)d_in[2];
  const float* ew   = (const float*)d_in[3];
  const int*   labels = (const int*)d_in[4];
  const float* W1   = (const float*)d_in[5];
  const float* b1   = (const float*)d_in[6];
  const float* W2   = (const float*)d_in[7];
  const float* b2   = (const float*)d_in[8];
  const float* Wsd  = (const float*)d_in[9];
  const float* bsd  = (const float*)d_in[10];
  float* out0 = (float*)d_out;
  float* out1 = out0 + (size_t)KSEL * 256;

  char* ws = (char*)d_ws;
  unsigned short* Xb   = (unsigned short*)(ws);               // 10,240,000 B
  unsigned short* Wt   = (unsigned short*)(ws + 10240000);    //    393,216 B
  unsigned short* supX = (unsigned short*)(ws + 10633216);    // 20,480,000 B  [N][512]: cols 0-255 X@W1, 256-511 X@Wsd
  unsigned short* h    = (unsigned short*)(ws + 31113216);    // 10,240,000 B
  unsigned short* s2   = (unsigned short*)(ws + 41353216);    // 10,240,000 B
  unsigned short* sel  = (unsigned short*)(ws + 51593216);    //  2,097,152 B
  int* idx    = (int*)(ws + 53690368);
  int* counts = (int*)(ws + 53706752);
  int* startp = (int*)(ws + 53786768);
  int* cursor = (int*)(ws + 53866784);
  int* perm   = (int*)(ws + 53946800);                        // ends ~55.2 MB

  hipMemsetAsync(counts, 0, NN * sizeof(int), stream);
  k_cvt_x<<<5000, 256, 0, stream>>>(X, Xb);
  k_cvt_w<<<768, 256, 0, stream>>>(W1, Wsd, W2, Wt);
  k_idx_scan<<<1, 1024, 0, stream>>>(labels, idx);
  k_hist<<<NE / 256, 256, 0, stream>>>(erow, counts);
  k_row_scan<<<1, 1024, 0, stream>>>(counts, startp, cursor);
  k_scatter<<<NE / 256, 256, 0, stream>>>(erow, cursor, perm);
  k_gemm<<<dim3(157, 8), 256, 0, stream>>>(Xb, Wt, supX, NN, 512);
  k_spmm1<<<5000, 256, 0, stream>>>(supX, startp, perm, ecol, ew, b1, h);
  k_gemm<<<dim3(157, 4), 256, 0, stream>>>(h, Wt + 512 * 256, s2, NN, 256);
  k_spmm2<<<1024, 256, 0, stream>>>(s2, idx, startp, perm, ecol, ew, b2, out0);
  k_spmm_sd<<<1024, 256, 0, stream>>>(supX, idx, startp, perm, ecol, ew, bsd, sel);
  k_gemm_st<<<dim3(32, 32), 256, 0, stream>>>(sel, out1);
}

// Round 2
// 282.576 us; speedup vs baseline: 1.3682x; 1.3682x over previous
//
#include <hip/hip_runtime.h>
#include <hip/hip_bf16.h>

#define NN   20000
#define NE   320000
#define KSEL 4096

typedef short bf16x8 __attribute__((ext_vector_type(8)));
typedef float f32x4  __attribute__((ext_vector_type(4)));

static __device__ __forceinline__ float bf2f(unsigned short u){
  return __uint_as_float(((unsigned int)u) << 16);
}
static __device__ __forceinline__ unsigned short f2bf(float f){
  unsigned int x = __float_as_uint(f);
  x += 0x7fffu + ((x >> 16) & 1u);   // round-to-nearest-even
  return (unsigned short)(x >> 16);
}

// ---------------- conversions ----------------
__global__ void k_cvt_x(const float* __restrict__ X, unsigned short* __restrict__ Xb){
  int i = (blockIdx.x * 256 + threadIdx.x) * 4;   // 5000*256*4 = 20000*256 exact
  float4 v = *(const float4*)(X + i);
  ushort4 o = { f2bf(v.x), f2bf(v.y), f2bf(v.z), f2bf(v.w) };
  *(ushort4*)(Xb + i) = o;
}

// Wt layout: rows [0,256)=W1^T, [256,512)=Wsd^T, [512,768)=W2^T; each row k-contiguous.
__global__ void k_cvt_w(const float* __restrict__ W1, const float* __restrict__ Wsd,
                        const float* __restrict__ W2, unsigned short* __restrict__ Wt){
  int t = blockIdx.x * 256 + threadIdx.x;  // 0 .. 3*65536-1
  int w = t >> 16;
  int o = (t >> 8) & 255;
  int k = t & 255;
  const float* W = (w == 0) ? W1 : (w == 1 ? Wsd : W2);
  Wt[t] = f2bf(W[k * 256 + o]);
}

// ---------------- shfl-based block scans (16 waves, 4 syncs per 1024-chunk) ----------------
__global__ __launch_bounds__(1024) void k_idx_scan(const int* __restrict__ labels,
                                                   int* __restrict__ idx){
  __shared__ int shw[16], shoff[16];
  __shared__ int carry_s, btot_s;
  int tid = threadIdx.x, lane = tid & 63, wv = tid >> 6;
  if (tid == 0) carry_s = 0;
  __syncthreads();
  for (int base = 0; base < NN; base += 1024){
    int n = base + tid;
    int v = (n < NN && labels[n] == 1) ? 1 : 0;
    int acc = v;
    #pragma unroll
    for (int off = 1; off < 64; off <<= 1){
      int t = __shfl_up(acc, off, 64);
      if (lane >= off) acc += t;
    }
    if (lane == 63) shw[wv] = acc;
    __syncthreads();
    if (wv == 0){
      int s = (lane < 16) ? shw[lane] : 0;
      #pragma unroll
      for (int off = 1; off < 16; off <<= 1){
        int t = __shfl_up(s, off, 64);
        if (lane >= off) s += t;
      }
      if (lane < 16) shoff[lane] = s - shw[lane];
      if (lane == 15) btot_s = s;
    }
    __syncthreads();
    int carry = carry_s;
    int incl = carry + shoff[wv] + acc;
    if (v){ int p = incl - 1; if (p < KSEL) idx[p] = n; }
    __syncthreads();
    if (tid == 0) carry_s = carry + btot_s;
    __syncthreads();
  }
}

__global__ __launch_bounds__(1024) void k_row_scan(const int* __restrict__ counts,
                                                   int* __restrict__ start,
                                                   int* __restrict__ cursor){
  __shared__ int shw[16], shoff[16];
  __shared__ int carry_s, btot_s;
  int tid = threadIdx.x, lane = tid & 63, wv = tid >> 6;
  if (tid == 0) carry_s = 0;
  __syncthreads();
  for (int base = 0; base < NN; base += 1024){
    int n = base + tid;
    int v = (n < NN) ? counts[n] : 0;
    int acc = v;
    #pragma unroll
    for (int off = 1; off < 64; off <<= 1){
      int t = __shfl_up(acc, off, 64);
      if (lane >= off) acc += t;
    }
    if (lane == 63) shw[wv] = acc;
    __syncthreads();
    if (wv == 0){
      int s = (lane < 16) ? shw[lane] : 0;
      #pragma unroll
      for (int off = 1; off < 16; off <<= 1){
        int t = __shfl_up(s, off, 64);
        if (lane >= off) s += t;
      }
      if (lane < 16) shoff[lane] = s - shw[lane];
      if (lane == 15) btot_s = s;
    }
    __syncthreads();
    int carry = carry_s;
    int incl = carry + shoff[wv] + acc;
    if (n < NN){ start[n] = incl - v; cursor[n] = incl - v; }
    __syncthreads();
    if (tid == 0) carry_s = carry + btot_s;
    __syncthreads();
  }
  if (tid == 0) start[NN] = carry_s;
}

// ---------------- CSR build ----------------
__global__ void k_hist(const int* __restrict__ row, int* __restrict__ counts){
  int e = blockIdx.x * 256 + threadIdx.x;
  if (e < NE) atomicAdd(&counts[row[e]], 1);
}

// scatter fused edge records {col, w} into CSR order — kills the perm indirection
__global__ void k_scatter(const int* __restrict__ row, const int* __restrict__ col,
                          const float* __restrict__ ew, int* __restrict__ cursor,
                          int2* __restrict__ rec){
  int e = blockIdx.x * 256 + threadIdx.x;
  if (e < NE){
    int r = row[e];
    int p = atomicAdd(&cursor[r], 1);
    rec[p] = make_int2(col[e], __float_as_int(ew[e]));
  }
}

// ---------------- bf16 MFMA GEMM: out[M,ldo] tile = A[M,256] @ Wt^T (Wt is [O][256]) ----
__global__ __launch_bounds__(256) void k_gemm(const unsigned short* __restrict__ A,
                                              const unsigned short* __restrict__ Wt,
                                              unsigned short* __restrict__ out,
                                              int M, int ldo){
  __shared__ unsigned short lds[64 * 264];
  int tid = threadIdx.x;
  int wave = tid >> 6, lane = tid & 63;
  int lm = lane & 15, lq = lane >> 4;
  int mBase = blockIdx.x * 128;
  int oBase = blockIdx.y * 64;
  #pragma unroll
  for (int it = 0; it < 8; ++it){
    int c = it * 256 + tid;
    int o = c >> 5, kk = (c & 31) << 3;
    *(bf16x8*)&lds[o * 264 + kk] = *(const bf16x8*)&Wt[(oBase + o) * 256 + kk];
  }
  __syncthreads();
  f32x4 acc[2][4] = {};
  int r0 = mBase + wave * 32 + lm;
  int r1 = r0 + 16;
  #pragma unroll
  for (int ks = 0; ks < 256; ks += 32){
    int ka = ks + lq * 8;
    bf16x8 a0 = {0,0,0,0,0,0,0,0}, a1 = {0,0,0,0,0,0,0,0};
    if (r0 < M) a0 = *(const bf16x8*)&A[(size_t)r0 * 256 + ka];
    if (r1 < M) a1 = *(const bf16x8*)&A[(size_t)r1 * 256 + ka];
    #pragma unroll
    for (int os = 0; os < 4; ++os){
      bf16x8 b = *(const bf16x8*)&lds[(os * 16 + lm) * 264 + ka];
      acc[0][os] = __builtin_amdgcn_mfma_f32_16x16x32_bf16(a0, b, acc[0][os], 0, 0, 0);
      acc[1][os] = __builtin_amdgcn_mfma_f32_16x16x32_bf16(a1, b, acc[1][os], 0, 0, 0);
    }
  }
  #pragma unroll
  for (int ms = 0; ms < 2; ++ms){
    int rb = mBase + wave * 32 + ms * 16 + lq * 4;
    #pragma unroll
    for (int os = 0; os < 4; ++os){
      int col = oBase + os * 16 + lm;
      #pragma unroll
      for (int r = 0; r < 4; ++r){
        int row = rb + r;
        if (row < M) out[(size_t)row * ldo + col] = f2bf(acc[ms][os][r]);
      }
    }
  }
}

// ---- small GEMM with f32 out + bias: out0 = aggH[4096,256] @ W2 + b2 ----
__global__ __launch_bounds__(256) void k_gemm_out(const unsigned short* __restrict__ A,
                                                  const unsigned short* __restrict__ Wt2,
                                                  const float* __restrict__ bias,
                                                  float* __restrict__ out){
  __shared__ unsigned short lds[64 * 264];
  int tid = threadIdx.x;
  int wave = tid >> 6, lane = tid & 63;
  int lm = lane & 15, lq = lane >> 4;
  int mBase = blockIdx.x * 128;
  int oBase = blockIdx.y * 64;
  #pragma unroll
  for (int it = 0; it < 8; ++it){
    int c = it * 256 + tid;
    int o = c >> 5, kk = (c & 31) << 3;
    *(bf16x8*)&lds[o * 264 + kk] = *(const bf16x8*)&Wt2[(oBase + o) * 256 + kk];
  }
  __syncthreads();
  f32x4 acc[2][4] = {};
  int r0 = mBase + wave * 32 + lm;
  #pragma unroll
  for (int ks = 0; ks < 256; ks += 32){
    int ka = ks + lq * 8;
    bf16x8 a0 = *(const bf16x8*)&A[(size_t)r0 * 256 + ka];
    bf16x8 a1 = *(const bf16x8*)&A[(size_t)(r0 + 16) * 256 + ka];
    #pragma unroll
    for (int os = 0; os < 4; ++os){
      bf16x8 b = *(const bf16x8*)&lds[(os * 16 + lm) * 264 + ka];
      acc[0][os] = __builtin_amdgcn_mfma_f32_16x16x32_bf16(a0, b, acc[0][os], 0, 0, 0);
      acc[1][os] = __builtin_amdgcn_mfma_f32_16x16x32_bf16(a1, b, acc[1][os], 0, 0, 0);
    }
  }
  #pragma unroll
  for (int ms = 0; ms < 2; ++ms){
    int rb = mBase + wave * 32 + ms * 16 + lq * 4;
    #pragma unroll
    for (int os = 0; os < 4; ++os){
      int col = oBase + os * 16 + lm;
      float bv = bias[col];
      #pragma unroll
      for (int r = 0; r < 4; ++r)
        out[(size_t)(rb + r) * 256 + col] = acc[ms][os][r] + bv;
    }
  }
}

// ---------------- s @ s^T : [4096,256] bf16 -> [4096,4096] f32 ----------------
__global__ __launch_bounds__(256) void k_gemm_st(const unsigned short* __restrict__ S,
                                                 float* __restrict__ out1){
  int tid = threadIdx.x, wave = tid >> 6, lane = tid & 63;
  int lm = lane & 15, lq = lane >> 4;
  int mBase = blockIdx.x * 128 + wave * 32;
  int oBase = blockIdx.y * 128;
  f32x4 acc[2][8] = {};
  #pragma unroll
  for (int ks = 0; ks < 256; ks += 32){
    int ka = ks + lq * 8;
    bf16x8 a0 = *(const bf16x8*)&S[(size_t)(mBase + lm) * 256 + ka];
    bf16x8 a1 = *(const bf16x8*)&S[(size_t)(mBase + 16 + lm) * 256 + ka];
    #pragma unroll
    for (int os = 0; os < 8; ++os){
      bf16x8 b = *(const bf16x8*)&S[(size_t)(oBase + os * 16 + lm) * 256 + ka];
      acc[0][os] = __builtin_amdgcn_mfma_f32_16x16x32_bf16(a0, b, acc[0][os], 0, 0, 0);
      acc[1][os] = __builtin_amdgcn_mfma_f32_16x16x32_bf16(a1, b, acc[1][os], 0, 0, 0);
    }
  }
  #pragma unroll
  for (int ms = 0; ms < 2; ++ms){
    int rb = mBase + ms * 16 + lq * 4;
    #pragma unroll
    for (int os = 0; os < 8; ++os){
      int col = oBase + os * 16 + lm;
      #pragma unroll
      for (int r = 0; r < 4; ++r)
        out1[(size_t)(rb + r) * 4096 + col] = acc[ms][os][r];
    }
  }
}

// ---------------- SpMM full: h = relu(A @ supX[:, :256] + b1) ----------------
// one wave per row; records preloaded into lanes, shfl-broadcast; 4 gathers in flight
__global__ __launch_bounds__(256) void k_spmm1(const unsigned short* __restrict__ supX,
    const int* __restrict__ start, const int2* __restrict__ rec,
    const float* __restrict__ b1, unsigned short* __restrict__ h){
  int wave = threadIdx.x >> 6, lane = threadIdx.x & 63;
  int n = blockIdx.x * 4 + wave;          // 5000*4 = 20000 exact
  int s = start[n], e = start[n + 1];
  int d = lane * 4;
  float a0 = 0, a1 = 0, a2 = 0, a3 = 0;
  for (int base = s; base < e; base += 64){
    int p = base + lane;
    int pc = p < e ? p : e - 1;
    int2 r = rec[pc];
    float wv = (p < e) ? __int_as_float(r.y) : 0.0f;
    int m = e - base; if (m > 64) m = 64;
    for (int j = 0; j < m; j += 4){
      int   c0 = __shfl(r.x, j),     c1 = __shfl(r.x, j + 1);
      int   c2 = __shfl(r.x, j + 2), c3 = __shfl(r.x, j + 3);
      float w0 = __shfl(wv, j),      w1 = __shfl(wv, j + 1);
      float w2 = __shfl(wv, j + 2),  w3 = __shfl(wv, j + 3);
      ushort4 v0 = *(const ushort4*)&supX[(size_t)c0 * 512 + d];
      ushort4 v1 = *(const ushort4*)&supX[(size_t)c1 * 512 + d];
      ushort4 v2 = *(const ushort4*)&supX[(size_t)c2 * 512 + d];
      ushort4 v3 = *(const ushort4*)&supX[(size_t)c3 * 512 + d];
      a0 += w0 * bf2f(v0.x) + w1 * bf2f(v1.x) + w2 * bf2f(v2.x) + w3 * bf2f(v3.x);
      a1 += w0 * bf2f(v0.y) + w1 * bf2f(v1.y) + w2 * bf2f(v2.y) + w3 * bf2f(v3.y);
      a2 += w0 * bf2f(v0.z) + w1 * bf2f(v1.z) + w2 * bf2f(v2.z) + w3 * bf2f(v3.z);
      a3 += w0 * bf2f(v0.w) + w1 * bf2f(v1.w) + w2 * bf2f(v2.w) + w3 * bf2f(v3.w);
    }
  }
  float4 b = *(const float4*)&b1[d];
  ushort4 o = { f2bf(fmaxf(a0 + b.x, 0.f)), f2bf(fmaxf(a1 + b.y, 0.f)),
                f2bf(fmaxf(a2 + b.z, 0.f)), f2bf(fmaxf(a3 + b.w, 0.f)) };
  *(ushort4*)&h[(size_t)n * 256 + d] = o;
}

// ---------------- fused selected SpMM: aggH = A[idx]@h ; sel = A[idx]@supX_sd + bsd ----
__global__ __launch_bounds__(256) void k_spmm_sel(const unsigned short* __restrict__ supX,
    const unsigned short* __restrict__ h, const int* __restrict__ idx,
    const int* __restrict__ start, const int2* __restrict__ rec,
    const float* __restrict__ bsd,
    unsigned short* __restrict__ aggH, unsigned short* __restrict__ sel){
  int wave = threadIdx.x >> 6, lane = threadIdx.x & 63;
  int i = blockIdx.x * 4 + wave;          // 1024*4 = 4096
  int n = idx[i];
  int s = start[n], e = start[n + 1];
  int d = lane * 4;
  float h0 = 0, h1 = 0, h2 = 0, h3 = 0;
  float s0 = 0, s1 = 0, s2 = 0, s3 = 0;
  for (int base = s; base < e; base += 64){
    int p = base + lane;
    int pc = p < e ? p : e - 1;
    int2 r = rec[pc];
    float wv = (p < e) ? __int_as_float(r.y) : 0.0f;
    int m = e - base; if (m > 64) m = 64;
    for (int j = 0; j < m; j += 2){
      int   c0 = __shfl(r.x, j), c1 = __shfl(r.x, j + 1);
      float w0 = __shfl(wv, j),  w1 = __shfl(wv, j + 1);
      ushort4 hv0 = *(const ushort4*)&h[(size_t)c0 * 256 + d];
      ushort4 sv0 = *(const ushort4*)&supX[(size_t)c0 * 512 + 256 + d];
      ushort4 hv1 = *(const ushort4*)&h[(size_t)c1 * 256 + d];
      ushort4 sv1 = *(const ushort4*)&supX[(size_t)c1 * 512 + 256 + d];
      h0 += w0 * bf2f(hv0.x) + w1 * bf2f(hv1.x);
      h1 += w0 * bf2f(hv0.y) + w1 * bf2f(hv1.y);
      h2 += w0 * bf2f(hv0.z) + w1 * bf2f(hv1.z);
      h3 += w0 * bf2f(hv0.w) + w1 * bf2f(hv1.w);
      s0 += w0 * bf2f(sv0.x) + w1 * bf2f(sv1.x);
      s1 += w0 * bf2f(sv0.y) + w1 * bf2f(sv1.y);
      s2 += w0 * bf2f(sv0.z) + w1 * bf2f(sv1.z);
      s3 += w0 * bf2f(sv0.w) + w1 * bf2f(sv1.w);
    }
  }
  ushort4 oh = { f2bf(h0), f2bf(h1), f2bf(h2), f2bf(h3) };
  *(ushort4*)&aggH[(size_t)i * 256 + d] = oh;
  float4 b = *(const float4*)&bsd[d];
  ushort4 os_ = { f2bf(s0 + b.x), f2bf(s1 + b.y), f2bf(s2 + b.z), f2bf(s3 + b.w) };
  *(ushort4*)&sel[(size_t)i * 256 + d] = os_;
}

extern "C" void kernel_launch(void* const* d_in, const int* in_sizes, int n_in,
                              void* d_out, int out_size, void* d_ws, size_t ws_size,
                              hipStream_t stream){
  const float* X    = (const float*)d_in[0];
  const int*   erow = (const int*)d_in[1];
  const int*   ecol = (const int*)d_in[2];
  const float* ew   = (const float*)d_in[3];
  const int*   labels = (const int*)d_in[4];
  const float* W1   = (const float*)d_in[5];
  const float* b1   = (const float*)d_in[6];
  const float* W2   = (const float*)d_in[7];
  const float* b2   = (const float*)d_in[8];
  const float* Wsd  = (const float*)d_in[9];
  const float* bsd  = (const float*)d_in[10];
  float* out0 = (float*)d_out;
  float* out1 = out0 + (size_t)KSEL * 256;

  char* ws = (char*)d_ws;
  unsigned short* Xb   = (unsigned short*)(ws);               // 10,240,000
  unsigned short* Wt   = (unsigned short*)(ws + 10240000);    //    393,216
  unsigned short* supX = (unsigned short*)(ws + 10633216);    // 20,480,000  [N][512]: 0-255 X@W1, 256-511 X@Wsd
  unsigned short* h    = (unsigned short*)(ws + 31113216);    // 10,240,000
  unsigned short* aggH = (unsigned short*)(ws + 41353216);    //  2,097,152
  unsigned short* sel  = (unsigned short*)(ws + 43450368);    //  2,097,152
  int* idx    = (int*)(ws + 45547520);                        //     16,384
  int* counts = (int*)(ws + 45563904);                        //     80,000
  int* startp = (int*)(ws + 45643904);                        //     80,004
  int* cursor = (int*)(ws + 45723908);                        //     80,000
  int2* rec   = (int2*)(ws + 45803912);                       //  2,560,000 (8B aligned)

  hipMemsetAsync(counts, 0, NN * sizeof(int), stream);
  k_cvt_x<<<5000, 256, 0, stream>>>(X, Xb);
  k_cvt_w<<<768, 256, 0, stream>>>(W1, Wsd, W2, Wt);
  k_idx_scan<<<1, 1024, 0, stream>>>(labels, idx);
  k_hist<<<NE / 256, 256, 0, stream>>>(erow, counts);
  k_row_scan<<<1, 1024, 0, stream>>>(counts, startp, cursor);
  k_scatter<<<NE / 256, 256, 0, stream>>>(erow, ecol, ew, cursor, rec);
  k_gemm<<<dim3(157, 8), 256, 0, stream>>>(Xb, Wt, supX, NN, 512);
  k_spmm1<<<5000, 256, 0, stream>>>(supX, startp, rec, b1, h);
  k_spmm_sel<<<1024, 256, 0, stream>>>(supX, h, idx, startp, rec, bsd, aggH, sel);
  k_gemm_out<<<dim3(32, 4), 256, 0, stream>>>(aggH, Wt + 512 * 256, b2, out0);
  k_gemm_st<<<dim3(32, 32), 256, 0, stream>>>(sel, out1);
}

// Round 3
// 224.727 us; speedup vs baseline: 1.7204x; 1.2574x over previous
//
#include <hip/hip_runtime.h>
#include <hip/hip_bf16.h>

#define NN   20000
#define NE   320000
#define KSEL 4096

typedef short bf16x8 __attribute__((ext_vector_type(8)));
typedef float f32x4  __attribute__((ext_vector_type(4)));

static __device__ __forceinline__ float bf2f(unsigned short u){
  return __uint_as_float(((unsigned int)u) << 16);
}
static __device__ __forceinline__ unsigned short f2bf(float f){
  unsigned int x = __float_as_uint(f);
  x += 0x7fffu + ((x >> 16) & 1u);   // round-to-nearest-even
  return (unsigned short)(x >> 16);
}
// async global->LDS, 16B/lane; LDS dest = wave-uniform base + lane*16
static __device__ __forceinline__ void gld_lds16(const unsigned short* g, unsigned short* l){
  __builtin_amdgcn_global_load_lds(
      (const __attribute__((address_space(1))) unsigned int*)g,
      (__attribute__((address_space(3))) unsigned int*)l, 16, 0, 0);
}

// ---------------- conversions ----------------
__global__ void k_cvt_x(const float* __restrict__ X, unsigned short* __restrict__ Xb){
  int i = (blockIdx.x * 256 + threadIdx.x) * 4;   // 5000*256*4 = 20000*256 exact
  float4 v = *(const float4*)(X + i);
  ushort4 o = { f2bf(v.x), f2bf(v.y), f2bf(v.z), f2bf(v.w) };
  *(ushort4*)(Xb + i) = o;
}

// Wt layout: rows [0,256)=W1^T, [256,512)=Wsd^T, [512,768)=W2^T; each row k-contiguous.
__global__ void k_cvt_w(const float* __restrict__ W1, const float* __restrict__ Wsd,
                        const float* __restrict__ W2, unsigned short* __restrict__ Wt){
  int t = blockIdx.x * 256 + threadIdx.x;  // 0 .. 3*65536-1
  int w = t >> 16;
  int o = (t >> 8) & 255;
  int k = t & 255;
  const float* W = (w == 0) ? W1 : (w == 1 ? Wsd : W2);
  Wt[t] = f2bf(W[k * 256 + o]);
}

// ---------------- 3-phase multi-block scans ----------------
// phase 1: per-block sums (block covers 1024 elems, 4/thread)
__global__ __launch_bounds__(256) void k_scan_part(const int* __restrict__ v, int n, int isLabel,
                                                   int* __restrict__ part){
  __shared__ int ws[4];
  int tid = threadIdx.x, lane = tid & 63, wv = tid >> 6;
  int base = blockIdx.x * 1024 + tid * 4;
  int s = 0;
  #pragma unroll
  for (int j = 0; j < 4; ++j){
    int n0 = base + j;
    if (n0 < n) s += isLabel ? (v[n0] == 1 ? 1 : 0) : v[n0];
  }
  #pragma unroll
  for (int off = 32; off; off >>= 1) s += __shfl_down(s, off, 64);
  if (lane == 0) ws[wv] = s;
  __syncthreads();
  if (tid == 0) part[blockIdx.x] = ws[0] + ws[1] + ws[2] + ws[3];
}

// phase 2: one wave, exclusive scan of P<=64 partials in place
__global__ __launch_bounds__(64) void k_scan_offs(int* __restrict__ part, int P){
  int lane = threadIdx.x;
  int v = (lane < P) ? part[lane] : 0;
  int acc = v;
  #pragma unroll
  for (int off = 1; off < 64; off <<= 1){
    int t = __shfl_up(acc, off, 64);
    if (lane >= off) acc += t;
  }
  if (lane < P) part[lane] = acc - v;
}

// phase 3a: emit idx = ascending positions of labels==1
__global__ __launch_bounds__(256) void k_idx_emit(const int* __restrict__ labels,
    const int* __restrict__ part, int* __restrict__ idx){
  __shared__ int ws[4];
  int tid = threadIdx.x, lane = tid & 63, wv = tid >> 6;
  int base = blockIdx.x * 1024 + tid * 4;
  int c[4]; int s = 0;
  #pragma unroll
  for (int j = 0; j < 4; ++j){
    int n0 = base + j;
    c[j] = (n0 < NN && labels[n0] == 1) ? 1 : 0;
    s += c[j];
  }
  int incl = s;
  #pragma unroll
  for (int off = 1; off < 64; off <<= 1){
    int t = __shfl_up(incl, off, 64);
    if (lane >= off) incl += t;
  }
  if (lane == 63) ws[wv] = incl;
  __syncthreads();
  int woff = part[blockIdx.x];
  for (int w = 0; w < wv; ++w) woff += ws[w];
  int off = woff + incl - s;
  #pragma unroll
  for (int j = 0; j < 4; ++j){
    if (c[j]){ if (off < KSEL) idx[off] = base + j; ++off; }
  }
}

// phase 3b: start/cursor from counts
__global__ __launch_bounds__(256) void k_row_emit(const int* __restrict__ counts,
    const int* __restrict__ part, int* __restrict__ start, int* __restrict__ cursor){
  __shared__ int ws[4];
  int tid = threadIdx.x, lane = tid & 63, wv = tid >> 6;
  int base = blockIdx.x * 1024 + tid * 4;
  int c[4]; int s = 0;
  #pragma unroll
  for (int j = 0; j < 4; ++j){
    int n0 = base + j;
    c[j] = (n0 < NN) ? counts[n0] : 0;
    s += c[j];
  }
  int incl = s;
  #pragma unroll
  for (int off = 1; off < 64; off <<= 1){
    int t = __shfl_up(incl, off, 64);
    if (lane >= off) incl += t;
  }
  if (lane == 63) ws[wv] = incl;
  __syncthreads();
  int woff = part[blockIdx.x];
  for (int w = 0; w < wv; ++w) woff += ws[w];
  int run = woff + incl - s;
  #pragma unroll
  for (int j = 0; j < 4; ++j){
    int n0 = base + j;
    if (n0 < NN){ start[n0] = run; cursor[n0] = run; run += c[j]; }
  }
  if (blockIdx.x == 0 && tid == 0) start[NN] = NE;   // total count is static
}

// ---------------- CSR build ----------------
__global__ void k_hist(const int* __restrict__ row, int* __restrict__ counts){
  int e = blockIdx.x * 256 + threadIdx.x;
  if (e < NE) atomicAdd(&counts[row[e]], 1);
}

__global__ void k_scatter(const int* __restrict__ row, const int* __restrict__ col,
                          const float* __restrict__ ew, int* __restrict__ cursor,
                          int2* __restrict__ rec){
  int e = blockIdx.x * 256 + threadIdx.x;
  if (e < NE){
    int r = row[e];
    int p = atomicAdd(&cursor[r], 1);
    rec[p] = make_int2(col[e], __float_as_int(ew[e]));
  }
}

// ---------------- staged bf16 MFMA GEMM: out[M,ldo] = A[M,256] @ Wt^T ----------------
// tile 128(M)x64(O), BK=64, global_load_lds staging with XOR chunk swizzle.
__global__ __launch_bounds__(256) void k_gemm(const unsigned short* __restrict__ A,
                                              const unsigned short* __restrict__ Wt,
                                              unsigned short* __restrict__ out,
                                              int M, int ldo){
  __shared__ unsigned short At[128 * 64];
  __shared__ unsigned short Bt[64 * 64];
  int tid = threadIdx.x, wave = tid >> 6, lane = tid & 63;
  int lm = lane & 15, lq = lane >> 4;
  int mBase = blockIdx.x * 128;
  int oBase = blockIdx.y * 64;
  f32x4 acc[2][4] = {};
  for (int kc = 0; kc < 256; kc += 64){
    if (kc) __syncthreads();
    #pragma unroll
    for (int it = 0; it < 4; ++it){
      int s = (wave * 4 + it) * 64 + lane;        // 0..1023
      int row = s >> 3, c = (s & 7) ^ (row & 7);
      int gr = mBase + row; if (gr >= M) gr = M - 1;
      gld_lds16(&A[(size_t)gr * 256 + kc + c * 8], &At[s * 8]);
    }
    #pragma unroll
    for (int it = 0; it < 2; ++it){
      int s = (wave * 2 + it) * 64 + lane;        // 0..511
      int row = s >> 3, c = (s & 7) ^ (row & 7);
      gld_lds16(&Wt[(size_t)(oBase + row) * 256 + kc + c * 8], &Bt[s * 8]);
    }
    __syncthreads();
    #pragma unroll
    for (int ks = 0; ks < 64; ks += 32){
      int cb = ks >> 3;
      int RA = wave * 32 + lm;
      int ca = ((cb + lq) ^ (RA & 7)) << 3;
      bf16x8 a0 = *(const bf16x8*)&At[RA * 64 + ca];
      bf16x8 a1 = *(const bf16x8*)&At[(RA + 16) * 64 + ca];
      #pragma unroll
      for (int os = 0; os < 4; ++os){
        int RB = os * 16 + lm;
        bf16x8 b = *(const bf16x8*)&Bt[RB * 64 + (((cb + lq) ^ (RB & 7)) << 3)];
        acc[0][os] = __builtin_amdgcn_mfma_f32_16x16x32_bf16(a0, b, acc[0][os], 0, 0, 0);
        acc[1][os] = __builtin_amdgcn_mfma_f32_16x16x32_bf16(a1, b, acc[1][os], 0, 0, 0);
      }
    }
  }
  #pragma unroll
  for (int ms = 0; ms < 2; ++ms){
    int rb = mBase + wave * 32 + ms * 16 + lq * 4;
    #pragma unroll
    for (int os = 0; os < 4; ++os){
      int col = oBase + os * 16 + lm;
      #pragma unroll
      for (int r = 0; r < 4; ++r){
        int row = rb + r;
        if (row < M) out[(size_t)row * ldo + col] = f2bf(acc[ms][os][r]);
      }
    }
  }
}

// ---- small GEMM with f32 out + bias: out0 = aggH[4096,256] @ W2 + b2 ----
__global__ __launch_bounds__(256) void k_gemm_out(const unsigned short* __restrict__ A,
                                                  const unsigned short* __restrict__ Wt2,
                                                  const float* __restrict__ bias,
                                                  float* __restrict__ out){
  __shared__ unsigned short lds[64 * 264];
  int tid = threadIdx.x;
  int wave = tid >> 6, lane = tid & 63;
  int lm = lane & 15, lq = lane >> 4;
  int mBase = blockIdx.x * 128;
  int oBase = blockIdx.y * 64;
  #pragma unroll
  for (int it = 0; it < 8; ++it){
    int c = it * 256 + tid;
    int o = c >> 5, kk = (c & 31) << 3;
    *(bf16x8*)&lds[o * 264 + kk] = *(const bf16x8*)&Wt2[(oBase + o) * 256 + kk];
  }
  __syncthreads();
  f32x4 acc[2][4] = {};
  int r0 = mBase + wave * 32 + lm;
  #pragma unroll
  for (int ks = 0; ks < 256; ks += 32){
    int ka = ks + lq * 8;
    bf16x8 a0 = *(const bf16x8*)&A[(size_t)r0 * 256 + ka];
    bf16x8 a1 = *(const bf16x8*)&A[(size_t)(r0 + 16) * 256 + ka];
    #pragma unroll
    for (int os = 0; os < 4; ++os){
      bf16x8 b = *(const bf16x8*)&lds[(os * 16 + lm) * 264 + ka];
      acc[0][os] = __builtin_amdgcn_mfma_f32_16x16x32_bf16(a0, b, acc[0][os], 0, 0, 0);
      acc[1][os] = __builtin_amdgcn_mfma_f32_16x16x32_bf16(a1, b, acc[1][os], 0, 0, 0);
    }
  }
  #pragma unroll
  for (int ms = 0; ms < 2; ++ms){
    int rb = mBase + wave * 32 + ms * 16 + lq * 4;
    #pragma unroll
    for (int os = 0; os < 4; ++os){
      int col = oBase + os * 16 + lm;
      float bv = bias[col];
      #pragma unroll
      for (int r = 0; r < 4; ++r)
        out[(size_t)(rb + r) * 256 + col] = acc[ms][os][r] + bv;
    }
  }
}

// ---------------- s @ s^T staged: [4096,256] bf16 -> [4096,4096] f32 ----------------
// tile 128x128, BK=64, LDS-staged both operands (m97 structure).
__global__ __launch_bounds__(256) void k_gemm_st(const unsigned short* __restrict__ S,
                                                 float* __restrict__ out1){
  __shared__ unsigned short At[128 * 64];
  __shared__ unsigned short Bt[128 * 64];
  int tid = threadIdx.x, wave = tid >> 6, lane = tid & 63;
  int lm = lane & 15, lq = lane >> 4;
  int mBase = blockIdx.x * 128;
  int oBase = blockIdx.y * 128;
  f32x4 acc[2][8] = {};
  for (int kc = 0; kc < 256; kc += 64){
    if (kc) __syncthreads();
    #pragma unroll
    for (int it = 0; it < 4; ++it){
      int s = (wave * 4 + it) * 64 + lane;        // 0..1023
      int row = s >> 3, c = (s & 7) ^ (row & 7);
      gld_lds16(&S[(size_t)(mBase + row) * 256 + kc + c * 8], &At[s * 8]);
      gld_lds16(&S[(size_t)(oBase + row) * 256 + kc + c * 8], &Bt[s * 8]);
    }
    __syncthreads();
    #pragma unroll
    for (int ks = 0; ks < 64; ks += 32){
      int cb = ks >> 3;
      int RA = wave * 32 + lm;
      int ca = ((cb + lq) ^ (RA & 7)) << 3;
      bf16x8 a0 = *(const bf16x8*)&At[RA * 64 + ca];
      bf16x8 a1 = *(const bf16x8*)&At[(RA + 16) * 64 + ca];
      #pragma unroll
      for (int os = 0; os < 8; ++os){
        int RB = os * 16 + lm;
        bf16x8 b = *(const bf16x8*)&Bt[RB * 64 + (((cb + lq) ^ (RB & 7)) << 3)];
        acc[0][os] = __builtin_amdgcn_mfma_f32_16x16x32_bf16(a0, b, acc[0][os], 0, 0, 0);
        acc[1][os] = __builtin_amdgcn_mfma_f32_16x16x32_bf16(a1, b, acc[1][os], 0, 0, 0);
      }
    }
  }
  #pragma unroll
  for (int ms = 0; ms < 2; ++ms){
    int rb = mBase + wave * 32 + ms * 16 + lq * 4;
    #pragma unroll
    for (int os = 0; os < 8; ++os){
      int col = oBase + os * 16 + lm;
      #pragma unroll
      for (int r = 0; r < 4; ++r)
        out1[(size_t)(rb + r) * 4096 + col] = acc[ms][os][r];
    }
  }
}

// ---------------- SpMM full: h = relu(A @ supX[:, :256] + b1) ----------------
__global__ __launch_bounds__(256) void k_spmm1(const unsigned short* __restrict__ supX,
    const int* __restrict__ start, const int2* __restrict__ rec,
    const float* __restrict__ b1, unsigned short* __restrict__ h){
  int wave = threadIdx.x >> 6, lane = threadIdx.x & 63;
  int n = blockIdx.x * 4 + wave;          // 5000*4 = 20000 exact
  int s = start[n], e = start[n + 1];
  int d = lane * 4;
  float a0 = 0, a1 = 0, a2 = 0, a3 = 0;
  for (int base = s; base < e; base += 64){
    int p = base + lane;
    int pc = p < e ? p : e - 1;
    int2 r = rec[pc];
    float wv = (p < e) ? __int_as_float(r.y) : 0.0f;
    int m = e - base; if (m > 64) m = 64;
    for (int j = 0; j < m; j += 4){
      int   c0 = __shfl(r.x, j),     c1 = __shfl(r.x, j + 1);
      int   c2 = __shfl(r.x, j + 2), c3 = __shfl(r.x, j + 3);
      float w0 = __shfl(wv, j),      w1 = __shfl(wv, j + 1);
      float w2 = __shfl(wv, j + 2),  w3 = __shfl(wv, j + 3);
      ushort4 v0 = *(const ushort4*)&supX[(size_t)c0 * 512 + d];
      ushort4 v1 = *(const ushort4*)&supX[(size_t)c1 * 512 + d];
      ushort4 v2 = *(const ushort4*)&supX[(size_t)c2 * 512 + d];
      ushort4 v3 = *(const ushort4*)&supX[(size_t)c3 * 512 + d];
      a0 += w0 * bf2f(v0.x) + w1 * bf2f(v1.x) + w2 * bf2f(v2.x) + w3 * bf2f(v3.x);
      a1 += w0 * bf2f(v0.y) + w1 * bf2f(v1.y) + w2 * bf2f(v2.y) + w3 * bf2f(v3.y);
      a2 += w0 * bf2f(v0.z) + w1 * bf2f(v1.z) + w2 * bf2f(v2.z) + w3 * bf2f(v3.z);
      a3 += w0 * bf2f(v0.w) + w1 * bf2f(v1.w) + w2 * bf2f(v2.w) + w3 * bf2f(v3.w);
    }
  }
  float4 b = *(const float4*)&b1[d];
  ushort4 o = { f2bf(fmaxf(a0 + b.x, 0.f)), f2bf(fmaxf(a1 + b.y, 0.f)),
                f2bf(fmaxf(a2 + b.z, 0.f)), f2bf(fmaxf(a3 + b.w, 0.f)) };
  *(ushort4*)&h[(size_t)n * 256 + d] = o;
}

// ---------------- fused selected SpMM: aggH = A[idx]@h ; sel = A[idx]@supX_sd + bsd ----
__global__ __launch_bounds__(256) void k_spmm_sel(const unsigned short* __restrict__ supX,
    const unsigned short* __restrict__ h, const int* __restrict__ idx,
    const int* __restrict__ start, const int2* __restrict__ rec,
    const float* __restrict__ bsd,
    unsigned short* __restrict__ aggH, unsigned short* __restrict__ sel){
  int wave = threadIdx.x >> 6, lane = threadIdx.x & 63;
  int i = blockIdx.x * 4 + wave;          // 1024*4 = 4096
  int n = idx[i];
  int s = start[n], e = start[n + 1];
  int d = lane * 4;
  float h0 = 0, h1 = 0, h2 = 0, h3 = 0;
  float s0 = 0, s1 = 0, s2 = 0, s3 = 0;
  for (int base = s; base < e; base += 64){
    int p = base + lane;
    int pc = p < e ? p : e - 1;
    int2 r = rec[pc];
    float wv = (p < e) ? __int_as_float(r.y) : 0.0f;
    int m = e - base; if (m > 64) m = 64;
    for (int j = 0; j < m; j += 2){
      int   c0 = __shfl(r.x, j), c1 = __shfl(r.x, j + 1);
      float w0 = __shfl(wv, j),  w1 = __shfl(wv, j + 1);
      ushort4 hv0 = *(const ushort4*)&h[(size_t)c0 * 256 + d];
      ushort4 sv0 = *(const ushort4*)&supX[(size_t)c0 * 512 + 256 + d];
      ushort4 hv1 = *(const ushort4*)&h[(size_t)c1 * 256 + d];
      ushort4 sv1 = *(const ushort4*)&supX[(size_t)c1 * 512 + 256 + d];
      h0 += w0 * bf2f(hv0.x) + w1 * bf2f(hv1.x);
      h1 += w0 * bf2f(hv0.y) + w1 * bf2f(hv1.y);
      h2 += w0 * bf2f(hv0.z) + w1 * bf2f(hv1.z);
      h3 += w0 * bf2f(hv0.w) + w1 * bf2f(hv1.w);
      s0 += w0 * bf2f(sv0.x) + w1 * bf2f(sv1.x);
      s1 += w0 * bf2f(sv0.y) + w1 * bf2f(sv1.y);
      s2 += w0 * bf2f(sv0.z) + w1 * bf2f(sv1.z);
      s3 += w0 * bf2f(sv0.w) + w1 * bf2f(sv1.w);
    }
  }
  ushort4 oh = { f2bf(h0), f2bf(h1), f2bf(h2), f2bf(h3) };
  *(ushort4*)&aggH[(size_t)i * 256 + d] = oh;
  float4 b = *(const float4*)&bsd[d];
  ushort4 os_ = { f2bf(s0 + b.x), f2bf(s1 + b.y), f2bf(s2 + b.z), f2bf(s3 + b.w) };
  *(ushort4*)&sel[(size_t)i * 256 + d] = os_;
}

extern "C" void kernel_launch(void* const* d_in, const int* in_sizes, int n_in,
                              void* d_out, int out_size, void* d_ws, size_t ws_size,
                              hipStream_t stream){
  const float* X    = (const float*)d_in[0];
  const int*   erow = (const int*)d_in[1];
  const int*   ecol = (const int*)d_in[2];
  const float* ew   = (const float*)d_in[3];
  const int*   labels = (const int*)d_in[4];
  const float* W1   = (const float*)d_in[5];
  const float* b1   = (const float*)d_in[6];
  const float* W2   = (const float*)d_in[7];
  const float* b2   = (const float*)d_in[8];
  const float* Wsd  = (const float*)d_in[9];
  const float* bsd  = (const float*)d_in[10];
  float* out0 = (float*)d_out;
  float* out1 = out0 + (size_t)KSEL * 256;

  char* ws = (char*)d_ws;
  unsigned short* Xb   = (unsigned short*)(ws);               // 10,240,000
  unsigned short* Wt   = (unsigned short*)(ws + 10240000);    //    393,216
  unsigned short* supX = (unsigned short*)(ws + 10633216);    // 20,480,000  [N][512]: 0-255 X@W1, 256-511 X@Wsd
  unsigned short* h    = (unsigned short*)(ws + 31113216);    // 10,240,000
  unsigned short* aggH = (unsigned short*)(ws + 41353216);    //  2,097,152
  unsigned short* sel  = (unsigned short*)(ws + 43450368);    //  2,097,152
  int* idx    = (int*)(ws + 45547520);                        //     16,384
  int* counts = (int*)(ws + 45563904);                        //     80,000
  int* startp = (int*)(ws + 45643904);                        //     80,004
  int* cursor = (int*)(ws + 45723908);                        //     80,000
  int2* rec   = (int2*)(ws + 45803912);                       //  2,560,000
  int* partA  = (int*)(ws + 48363912);                        //        128
  int* partB  = (int*)(ws + 48364040);                        //        128

  hipMemsetAsync(counts, 0, NN * sizeof(int), stream);
  k_cvt_x<<<5000, 256, 0, stream>>>(X, Xb);
  k_cvt_w<<<768, 256, 0, stream>>>(W1, Wsd, W2, Wt);
  k_scan_part<<<20, 256, 0, stream>>>(labels, NN, 1, partA);
  k_scan_offs<<<1, 64, 0, stream>>>(partA, 20);
  k_idx_emit<<<20, 256, 0, stream>>>(labels, partA, idx);
  k_hist<<<NE / 256, 256, 0, stream>>>(erow, counts);
  k_scan_part<<<20, 256, 0, stream>>>(counts, NN, 0, partB);
  k_scan_offs<<<1, 64, 0, stream>>>(partB, 20);
  k_row_emit<<<20, 256, 0, stream>>>(counts, partB, startp, cursor);
  k_scatter<<<NE / 256, 256, 0, stream>>>(erow, ecol, ew, cursor, rec);
  k_gemm<<<dim3(157, 8), 256, 0, stream>>>(Xb, Wt, supX, NN, 512);
  k_spmm1<<<5000, 256, 0, stream>>>(supX, startp, rec, b1, h);
  k_spmm_sel<<<1024, 256, 0, stream>>>(supX, h, idx, startp, rec, bsd, aggH, sel);
  k_gemm_out<<<dim3(32, 4), 256, 0, stream>>>(aggH, Wt + 512 * 256, b2, out0);
  k_gemm_st<<<dim3(32, 32), 256, 0, stream>>>(sel, out1);
}

// Round 4
// 208.080 us; speedup vs baseline: 1.8580x; 1.0800x over previous
//
#include <hip/hip_runtime.h>
#include <hip/hip_bf16.h>

#define NN   20000
#define NE   320000
#define KSEL 4096

typedef short bf16x8 __attribute__((ext_vector_type(8)));
typedef float f32x4  __attribute__((ext_vector_type(4)));

static __device__ __forceinline__ float bf2f(unsigned short u){
  return __uint_as_float(((unsigned int)u) << 16);
}
static __device__ __forceinline__ unsigned short f2bf(float f){
  unsigned int x = __float_as_uint(f);
  x += 0x7fffu + ((x >> 16) & 1u);   // round-to-nearest-even
  return (unsigned short)(x >> 16);
}
// async global->LDS, 16B/lane; LDS dest = wave-uniform base + lane*16
static __device__ __forceinline__ void gld_lds16(const unsigned short* g, unsigned short* l){
  __builtin_amdgcn_global_load_lds(
      (const __attribute__((address_space(1))) unsigned int*)g,
      (__attribute__((address_space(3))) unsigned int*)l, 16, 0, 0);
}

// ---------------- fused prep: cvt X, cvt W, zero counts, label partials ----------------
// blocks [0,5000): X->bf16 ; [5000,5768): W1|Wsd|W2 -> Wt^T ; [5768,5788): zero counts + partA
__global__ __launch_bounds__(256) void k_prep(const float* __restrict__ X,
    const float* __restrict__ W1, const float* __restrict__ Wsd, const float* __restrict__ W2,
    const int* __restrict__ labels,
    unsigned short* __restrict__ Xb, unsigned short* __restrict__ Wt,
    int* __restrict__ counts, int* __restrict__ partA){
  int b = blockIdx.x, tid = threadIdx.x;
  if (b < 5000){
    int i = (b * 256 + tid) * 4;
    float4 v = *(const float4*)(X + i);
    ushort4 o = { f2bf(v.x), f2bf(v.y), f2bf(v.z), f2bf(v.w) };
    *(ushort4*)(Xb + i) = o;
  } else if (b < 5768){
    int t = (b - 5000) * 256 + tid;
    int w = t >> 16, o = (t >> 8) & 255, k = t & 255;
    const float* W = (w == 0) ? W1 : (w == 1 ? Wsd : W2);
    Wt[t] = f2bf(W[k * 256 + o]);
  } else {
    __shared__ int ws[4];
    int z = b - 5768, lane = tid & 63, wv = tid >> 6;
    // zero counts window [z*1000, z*1000+1000)
    if (tid < 250) *(int4*)&counts[z * 1000 + tid * 4] = make_int4(0, 0, 0, 0);
    // label partial sum over window [z*1024, z*1024+1024)
    int base = z * 1024 + tid * 4;
    int s = 0;
    #pragma unroll
    for (int j = 0; j < 4; ++j){
      int n0 = base + j;
      if (n0 < NN) s += (labels[n0] == 1) ? 1 : 0;
    }
    #pragma unroll
    for (int off = 32; off; off >>= 1) s += __shfl_down(s, off, 64);
    if (lane == 0) ws[wv] = s;
    __syncthreads();
    if (tid == 0) partA[z] = ws[0] + ws[1] + ws[2] + ws[3];
  }
}

// ---------------- CSR build ----------------
__global__ void k_hist(const int* __restrict__ row, int* __restrict__ counts){
  int e = blockIdx.x * 256 + threadIdx.x;
  if (e < NE) atomicAdd(&counts[row[e]], 1);
}

// 20 blocks; each computes global offset from partA in-register, then emits its idx window
__global__ __launch_bounds__(256) void k_idx_emit(const int* __restrict__ labels,
    const int* __restrict__ partA, int* __restrict__ idx){
  __shared__ int ws[4];
  __shared__ int boff_s;
  int tid = threadIdx.x, lane = tid & 63, wv = tid >> 6;
  if (tid < 64){
    int v = (lane < 20) ? partA[lane] : 0;
    int acc = v;
    #pragma unroll
    for (int off = 1; off < 32; off <<= 1){
      int t = __shfl_up(acc, off, 64);
      if (lane >= off) acc += t;
    }
    if (lane == (int)blockIdx.x) boff_s = acc - v;   // exclusive prefix
  }
  int base = blockIdx.x * 1024 + tid * 4;
  int c[4]; int s = 0;
  #pragma unroll
  for (int j = 0; j < 4; ++j){
    int n0 = base + j;
    c[j] = (n0 < NN && labels[n0] == 1) ? 1 : 0;
    s += c[j];
  }
  int incl = s;
  #pragma unroll
  for (int off = 1; off < 64; off <<= 1){
    int t = __shfl_up(incl, off, 64);
    if (lane >= off) incl += t;
  }
  if (lane == 63) ws[wv] = incl;
  __syncthreads();
  int woff = boff_s;
  for (int w = 0; w < wv; ++w) woff += ws[w];
  int off = woff + incl - s;
  #pragma unroll
  for (int j = 0; j < 4; ++j){
    if (c[j]){ if (off < KSEL) idx[off] = base + j; ++off; }
  }
}

// 20 blocks; each sums counts[0..base) itself, then scans its 1024-window -> start/cursor
__global__ __launch_bounds__(256) void k_row_emit(const int* __restrict__ counts,
    int* __restrict__ start, int* __restrict__ cursor){
  __shared__ int ws[4];
  __shared__ int red[4];
  int tid = threadIdx.x, lane = tid & 63, wv = tid >> 6;
  int base = blockIdx.x * 1024;
  // block prefix: sum counts[0..base)
  int ps = 0;
  for (int i = tid * 4; i < base; i += 1024){
    int4 v = *(const int4*)&counts[i];
    ps += v.x + v.y + v.z + v.w;
  }
  #pragma unroll
  for (int off = 32; off; off >>= 1) ps += __shfl_down(ps, off, 64);
  if (lane == 0) red[wv] = ps;
  __syncthreads();
  int bpref = red[0] + red[1] + red[2] + red[3];
  // window scan
  int nb = base + tid * 4;
  int c[4]; int s = 0;
  #pragma unroll
  for (int j = 0; j < 4; ++j){
    int n0 = nb + j;
    c[j] = (n0 < NN) ? counts[n0] : 0;
    s += c[j];
  }
  int incl = s;
  #pragma unroll
  for (int off = 1; off < 64; off <<= 1){
    int t = __shfl_up(incl, off, 64);
    if (lane >= off) incl += t;
  }
  if (lane == 63) ws[wv] = incl;
  __syncthreads();
  int woff = bpref;
  for (int w = 0; w < wv; ++w) woff += ws[w];
  int run = woff + incl - s;
  #pragma unroll
  for (int j = 0; j < 4; ++j){
    int n0 = nb + j;
    if (n0 < NN){ start[n0] = run; cursor[n0] = run; run += c[j]; }
  }
  if (blockIdx.x == 0 && tid == 0) start[NN] = NE;
}

__global__ void k_scatter(const int* __restrict__ row, const int* __restrict__ col,
                          const float* __restrict__ ew, int* __restrict__ cursor,
                          int2* __restrict__ rec){
  int e = blockIdx.x * 256 + threadIdx.x;
  if (e < NE){
    int r = row[e];
    int p = atomicAdd(&cursor[r], 1);
    rec[p] = make_int2(col[e], __float_as_int(ew[e]));
  }
}

// ---------------- full SpMM: aggX = A @ Xb  (20000x256 bf16) ----------------
__global__ __launch_bounds__(256) void k_spmm_full(const unsigned short* __restrict__ Xb,
    const int* __restrict__ start, const int2* __restrict__ rec,
    unsigned short* __restrict__ aggX){
  int wave = threadIdx.x >> 6, lane = threadIdx.x & 63;
  int n = blockIdx.x * 4 + wave;          // 5000*4 = 20000 exact
  int s = start[n], e = start[n + 1];
  int d = lane * 4;
  float a0 = 0, a1 = 0, a2 = 0, a3 = 0;
  for (int base = s; base < e; base += 64){
    int p = base + lane;
    int pc = p < e ? p : e - 1;
    int2 r = rec[pc];
    float wv = (p < e) ? __int_as_float(r.y) : 0.0f;
    int m = e - base; if (m > 64) m = 64;
    for (int j = 0; j < m; j += 4){
      int   c0 = __shfl(r.x, j),     c1 = __shfl(r.x, j + 1);
      int   c2 = __shfl(r.x, j + 2), c3 = __shfl(r.x, j + 3);
      float w0 = __shfl(wv, j),      w1 = __shfl(wv, j + 1);
      float w2 = __shfl(wv, j + 2),  w3 = __shfl(wv, j + 3);
      ushort4 v0 = *(const ushort4*)&Xb[(size_t)c0 * 256 + d];
      ushort4 v1 = *(const ushort4*)&Xb[(size_t)c1 * 256 + d];
      ushort4 v2 = *(const ushort4*)&Xb[(size_t)c2 * 256 + d];
      ushort4 v3 = *(const ushort4*)&Xb[(size_t)c3 * 256 + d];
      a0 += w0 * bf2f(v0.x) + w1 * bf2f(v1.x) + w2 * bf2f(v2.x) + w3 * bf2f(v3.x);
      a1 += w0 * bf2f(v0.y) + w1 * bf2f(v1.y) + w2 * bf2f(v2.y) + w3 * bf2f(v3.y);
      a2 += w0 * bf2f(v0.z) + w1 * bf2f(v1.z) + w2 * bf2f(v2.z) + w3 * bf2f(v3.z);
      a3 += w0 * bf2f(v0.w) + w1 * bf2f(v1.w) + w2 * bf2f(v2.w) + w3 * bf2f(v3.w);
    }
  }
  ushort4 o = { f2bf(a0), f2bf(a1), f2bf(a2), f2bf(a3) };
  *(ushort4*)&aggX[(size_t)n * 256 + d] = o;
}

// ---------------- staged GEMM + bias + relu: h = relu(aggX @ W1^T + b1) ----------------
// tile 128(M)x64(O), BK=64, global_load_lds with XOR chunk swizzle (validated r3 structure).
__global__ __launch_bounds__(256) void k_gemm_h(const unsigned short* __restrict__ A,
                                                const unsigned short* __restrict__ Wt,
                                                const float* __restrict__ bias,
                                                unsigned short* __restrict__ out, int M){
  __shared__ unsigned short At[128 * 64];
  __shared__ unsigned short Bt[64 * 64];
  int tid = threadIdx.x, wave = tid >> 6, lane = tid & 63;
  int lm = lane & 15, lq = lane >> 4;
  int mBase = blockIdx.x * 128;
  int oBase = blockIdx.y * 64;
  f32x4 acc[2][4] = {};
  for (int kc = 0; kc < 256; kc += 64){
    if (kc) __syncthreads();
    #pragma unroll
    for (int it = 0; it < 4; ++it){
      int s = (wave * 4 + it) * 64 + lane;
      int row = s >> 3, c = (s & 7) ^ (row & 7);
      int gr = mBase + row; if (gr >= M) gr = M - 1;
      gld_lds16(&A[(size_t)gr * 256 + kc + c * 8], &At[s * 8]);
    }
    #pragma unroll
    for (int it = 0; it < 2; ++it){
      int s = (wave * 2 + it) * 64 + lane;
      int row = s >> 3, c = (s & 7) ^ (row & 7);
      gld_lds16(&Wt[(size_t)(oBase + row) * 256 + kc + c * 8], &Bt[s * 8]);
    }
    __syncthreads();
    #pragma unroll
    for (int ks = 0; ks < 64; ks += 32){
      int cb = ks >> 3;
      int RA = wave * 32 + lm;
      int ca = ((cb + lq) ^ (RA & 7)) << 3;
      bf16x8 a0 = *(const bf16x8*)&At[RA * 64 + ca];
      bf16x8 a1 = *(const bf16x8*)&At[(RA + 16) * 64 + ca];
      #pragma unroll
      for (int os = 0; os < 4; ++os){
        int RB = os * 16 + lm;
        bf16x8 b = *(const bf16x8*)&Bt[RB * 64 + (((cb + lq) ^ (RB & 7)) << 3)];
        acc[0][os] = __builtin_amdgcn_mfma_f32_16x16x32_bf16(a0, b, acc[0][os], 0, 0, 0);
        acc[1][os] = __builtin_amdgcn_mfma_f32_16x16x32_bf16(a1, b, acc[1][os], 0, 0, 0);
      }
    }
  }
  #pragma unroll
  for (int ms = 0; ms < 2; ++ms){
    int rb = mBase + wave * 32 + ms * 16 + lq * 4;
    #pragma unroll
    for (int os = 0; os < 4; ++os){
      int col = oBase + os * 16 + lm;
      float bv = bias[col];
      #pragma unroll
      for (int r = 0; r < 4; ++r){
        int row = rb + r;
        if (row < M) out[(size_t)row * 256 + col] = f2bf(fmaxf(acc[ms][os][r] + bv, 0.f));
      }
    }
  }
}

// ---------------- selected SpMM: aggH = A[idx] @ h  (4096x256 bf16) ----------------
__global__ __launch_bounds__(256) void k_spmm_selH(const unsigned short* __restrict__ h,
    const int* __restrict__ idx, const int* __restrict__ start, const int2* __restrict__ rec,
    unsigned short* __restrict__ aggH){
  int wave = threadIdx.x >> 6, lane = threadIdx.x & 63;
  int i = blockIdx.x * 4 + wave;          // 1024*4 = 4096
  int n = idx[i];
  int s = start[n], e = start[n + 1];
  int d = lane * 4;
  float a0 = 0, a1 = 0, a2 = 0, a3 = 0;
  for (int base = s; base < e; base += 64){
    int p = base + lane;
    int pc = p < e ? p : e - 1;
    int2 r = rec[pc];
    float wv = (p < e) ? __int_as_float(r.y) : 0.0f;
    int m = e - base; if (m > 64) m = 64;
    for (int j = 0; j < m; j += 4){
      int   c0 = __shfl(r.x, j),     c1 = __shfl(r.x, j + 1);
      int   c2 = __shfl(r.x, j + 2), c3 = __shfl(r.x, j + 3);
      float w0 = __shfl(wv, j),      w1 = __shfl(wv, j + 1);
      float w2 = __shfl(wv, j + 2),  w3 = __shfl(wv, j + 3);
      ushort4 v0 = *(const ushort4*)&h[(size_t)c0 * 256 + d];
      ushort4 v1 = *(const ushort4*)&h[(size_t)c1 * 256 + d];
      ushort4 v2 = *(const ushort4*)&h[(size_t)c2 * 256 + d];
      ushort4 v3 = *(const ushort4*)&h[(size_t)c3 * 256 + d];
      a0 += w0 * bf2f(v0.x) + w1 * bf2f(v1.x) + w2 * bf2f(v2.x) + w3 * bf2f(v3.x);
      a1 += w0 * bf2f(v0.y) + w1 * bf2f(v1.y) + w2 * bf2f(v2.y) + w3 * bf2f(v3.y);
      a2 += w0 * bf2f(v0.z) + w1 * bf2f(v1.z) + w2 * bf2f(v2.z) + w3 * bf2f(v3.z);
      a3 += w0 * bf2f(v0.w) + w1 * bf2f(v1.w) + w2 * bf2f(v2.w) + w3 * bf2f(v3.w);
    }
  }
  ushort4 o = { f2bf(a0), f2bf(a1), f2bf(a2), f2bf(a3) };
  *(ushort4*)&aggH[(size_t)i * 256 + d] = o;
}

// ---- fused small GEMMs (z=0: out0 = aggH@W2+b2 f32 ; z=1: sel = aggX[idx]@Wsd+bsd bf16) ----
__global__ __launch_bounds__(256) void k_gemm_os(const unsigned short* __restrict__ aggH,
    const unsigned short* __restrict__ aggX, const int* __restrict__ idx,
    const unsigned short* __restrict__ Wt,
    const float* __restrict__ b2, const float* __restrict__ bsd,
    float* __restrict__ out0, unsigned short* __restrict__ sel){
  __shared__ unsigned short lds[64 * 264];
  int tid = threadIdx.x;
  int wave = tid >> 6, lane = tid & 63;
  int lm = lane & 15, lq = lane >> 4;
  int z = blockIdx.z;
  int mBase = blockIdx.x * 128;
  int oBase = blockIdx.y * 64;
  const unsigned short* Wt2 = Wt + (z ? 256 * 256 : 512 * 256);
  const float* bias = z ? bsd : b2;
  #pragma unroll
  for (int it = 0; it < 8; ++it){
    int c = it * 256 + tid;
    int o = c >> 5, kk = (c & 31) << 3;
    *(bf16x8*)&lds[o * 264 + kk] = *(const bf16x8*)&Wt2[(oBase + o) * 256 + kk];
  }
  __syncthreads();
  int r0 = mBase + wave * 32 + lm;
  const unsigned short* A0;
  const unsigned short* A1;
  if (z){
    A0 = aggX + (size_t)idx[r0] * 256;
    A1 = aggX + (size_t)idx[r0 + 16] * 256;
  } else {
    A0 = aggH + (size_t)r0 * 256;
    A1 = aggH + (size_t)(r0 + 16) * 256;
  }
  f32x4 acc[2][4] = {};
  #pragma unroll
  for (int ks = 0; ks < 256; ks += 32){
    int ka = ks + lq * 8;
    bf16x8 a0 = *(const bf16x8*)&A0[ka];
    bf16x8 a1 = *(const bf16x8*)&A1[ka];
    #pragma unroll
    for (int os = 0; os < 4; ++os){
      bf16x8 b = *(const bf16x8*)&lds[(os * 16 + lm) * 264 + ka];
      acc[0][os] = __builtin_amdgcn_mfma_f32_16x16x32_bf16(a0, b, acc[0][os], 0, 0, 0);
      acc[1][os] = __builtin_amdgcn_mfma_f32_16x16x32_bf16(a1, b, acc[1][os], 0, 0, 0);
    }
  }
  #pragma unroll
  for (int ms = 0; ms < 2; ++ms){
    int rb = mBase + wave * 32 + ms * 16 + lq * 4;
    #pragma unroll
    for (int os = 0; os < 4; ++os){
      int col = oBase + os * 16 + lm;
      float bv = bias[col];
      #pragma unroll
      for (int r = 0; r < 4; ++r){
        float v = acc[ms][os][r] + bv;
        if (z) sel[(size_t)(rb + r) * 256 + col] = f2bf(v);
        else   out0[(size_t)(rb + r) * 256 + col] = v;
      }
    }
  }
}

// ---------------- s @ s^T staged: [4096,256] bf16 -> [4096,4096] f32 ----------------
__global__ __launch_bounds__(256) void k_gemm_st(const unsigned short* __restrict__ S,
                                                 float* __restrict__ out1){
  __shared__ unsigned short At[128 * 64];
  __shared__ unsigned short Bt[128 * 64];
  int tid = threadIdx.x, wave = tid >> 6, lane = tid & 63;
  int lm = lane & 15, lq = lane >> 4;
  int mBase = blockIdx.x * 128;
  int oBase = blockIdx.y * 128;
  f32x4 acc[2][8] = {};
  for (int kc = 0; kc < 256; kc += 64){
    if (kc) __syncthreads();
    #pragma unroll
    for (int it = 0; it < 4; ++it){
      int s = (wave * 4 + it) * 64 + lane;
      int row = s >> 3, c = (s & 7) ^ (row & 7);
      gld_lds16(&S[(size_t)(mBase + row) * 256 + kc + c * 8], &At[s * 8]);
      gld_lds16(&S[(size_t)(oBase + row) * 256 + kc + c * 8], &Bt[s * 8]);
    }
    __syncthreads();
    #pragma unroll
    for (int ks = 0; ks < 64; ks += 32){
      int cb = ks >> 3;
      int RA = wave * 32 + lm;
      int ca = ((cb + lq) ^ (RA & 7)) << 3;
      bf16x8 a0 = *(const bf16x8*)&At[RA * 64 + ca];
      bf16x8 a1 = *(const bf16x8*)&At[(RA + 16) * 64 + ca];
      #pragma unroll
      for (int os = 0; os < 8; ++os){
        int RB = os * 16 + lm;
        bf16x8 b = *(const bf16x8*)&Bt[RB * 64 + (((cb + lq) ^ (RB & 7)) << 3)];
        acc[0][os] = __builtin_amdgcn_mfma_f32_16x16x32_bf16(a0, b, acc[0][os], 0, 0, 0);
        acc[1][os] = __builtin_amdgcn_mfma_f32_16x16x32_bf16(a1, b, acc[1][os], 0, 0, 0);
      }
    }
  }
  #pragma unroll
  for (int ms = 0; ms < 2; ++ms){
    int rb = mBase + wave * 32 + ms * 16 + lq * 4;
    #pragma unroll
    for (int os = 0; os < 8; ++os){
      int col = oBase + os * 16 + lm;
      #pragma unroll
      for (int r = 0; r < 4; ++r)
        out1[(size_t)(rb + r) * 4096 + col] = acc[ms][os][r];
    }
  }
}

extern "C" void kernel_launch(void* const* d_in, const int* in_sizes, int n_in,
                              void* d_out, int out_size, void* d_ws, size_t ws_size,
                              hipStream_t stream){
  const float* X    = (const float*)d_in[0];
  const int*   erow = (const int*)d_in[1];
  const int*   ecol = (const int*)d_in[2];
  const float* ew   = (const float*)d_in[3];
  const int*   labels = (const int*)d_in[4];
  const float* W1   = (const float*)d_in[5];
  const float* b1   = (const float*)d_in[6];
  const float* W2   = (const float*)d_in[7];
  const float* b2   = (const float*)d_in[8];
  const float* Wsd  = (const float*)d_in[9];
  const float* bsd  = (const float*)d_in[10];
  float* out0 = (float*)d_out;
  float* out1 = out0 + (size_t)KSEL * 256;

  char* ws = (char*)d_ws;
  unsigned short* Xb   = (unsigned short*)(ws);               // 10,240,000
  unsigned short* Wt   = (unsigned short*)(ws + 10240000);    //    393,216
  unsigned short* aggX = (unsigned short*)(ws + 10633216);    // 10,240,000
  unsigned short* h    = (unsigned short*)(ws + 20873216);    // 10,240,000
  unsigned short* aggH = (unsigned short*)(ws + 31113216);    //  2,097,152
  unsigned short* sel  = (unsigned short*)(ws + 33210368);    //  2,097,152
  int* idx    = (int*)(ws + 35307520);                        //     16,384
  int* counts = (int*)(ws + 35323904);                        //     80,000
  int* startp = (int*)(ws + 35403904);                        //     80,004
  int* cursor = (int*)(ws + 35483908);                        //     80,000
  int2* rec   = (int2*)(ws + 35563912);                       //  2,560,000
  int* partA  = (int*)(ws + 38123912);                        //        128

  k_prep<<<5788, 256, 0, stream>>>(X, W1, Wsd, W2, labels, Xb, Wt, counts, partA);
  k_hist<<<NE / 256, 256, 0, stream>>>(erow, counts);
  k_idx_emit<<<20, 256, 0, stream>>>(labels, partA, idx);
  k_row_emit<<<20, 256, 0, stream>>>(counts, startp, cursor);
  k_scatter<<<NE / 256, 256, 0, stream>>>(erow, ecol, ew, cursor, rec);
  k_spmm_full<<<5000, 256, 0, stream>>>(Xb, startp, rec, aggX);
  k_gemm_h<<<dim3(157, 4), 256, 0, stream>>>(aggX, Wt, b1, h, NN);
  k_spmm_selH<<<1024, 256, 0, stream>>>(h, idx, startp, rec, aggH);
  k_gemm_os<<<dim3(32, 4, 2), 256, 0, stream>>>(aggH, aggX, idx, Wt, b2, bsd, out0, sel);
  k_gemm_st<<<dim3(32, 32), 256, 0, stream>>>(sel, out1);
}

// Round 5
// 205.238 us; speedup vs baseline: 1.8838x; 1.0138x over previous
//
#include <hip/hip_runtime.h>
#include <hip/hip_bf16.h>

#define NN   20000
#define NE   320000
#define KSEL 4096

typedef short bf16x8 __attribute__((ext_vector_type(8)));
typedef float f32x4  __attribute__((ext_vector_type(4)));

static __device__ __forceinline__ float bf2f(unsigned short u){
  return __uint_as_float(((unsigned int)u) << 16);
}
static __device__ __forceinline__ unsigned short f2bf(float f){
  unsigned int x = __float_as_uint(f);
  x += 0x7fffu + ((x >> 16) & 1u);   // round-to-nearest-even
  return (unsigned short)(x >> 16);
}
// async global->LDS, 16B/lane; LDS dest = wave-uniform base + lane*16
static __device__ __forceinline__ void gld_lds16(const unsigned short* g, unsigned short* l){
  __builtin_amdgcn_global_load_lds(
      (const __attribute__((address_space(1))) unsigned int*)g,
      (__attribute__((address_space(3))) unsigned int*)l, 16, 0, 0);
}

// ---------------- fused prep ----------------
// blocks [0,2500): X->bf16 (8 elems/thread) ; [2500,2548): W 64x64 tile-transpose via LDS ;
// [2548,2568): zero counts + label partials
__global__ __launch_bounds__(256) void k_prep(const float* __restrict__ X,
    const float* __restrict__ W1, const float* __restrict__ Wsd, const float* __restrict__ W2,
    const int* __restrict__ labels,
    unsigned short* __restrict__ Xb, unsigned short* __restrict__ Wt,
    int* __restrict__ counts, int* __restrict__ partA){
  int b = blockIdx.x, tid = threadIdx.x;
  if (b < 2500){
    int i = (b * 256 + tid) * 8;
    float4 v0 = *(const float4*)(X + i);
    float4 v1 = *(const float4*)(X + i + 4);
    bf16x8 o;
    o[0] = (short)f2bf(v0.x); o[1] = (short)f2bf(v0.y);
    o[2] = (short)f2bf(v0.z); o[3] = (short)f2bf(v0.w);
    o[4] = (short)f2bf(v1.x); o[5] = (short)f2bf(v1.y);
    o[6] = (short)f2bf(v1.z); o[7] = (short)f2bf(v1.w);
    *(bf16x8*)(Xb + i) = o;
  } else if (b < 2548){
    __shared__ unsigned short lt[64 * 65];
    int b2 = b - 2500;
    int w = b2 >> 4, t = b2 & 15;
    int tR = (t >> 2) * 64, tC = (t & 3) * 64;    // k-block, o-block
    const float* W = (w == 0) ? W1 : (w == 1 ? Wsd : W2);
    #pragma unroll
    for (int it = 0; it < 16; ++it){
      int lin = it * 256 + tid;
      int r = lin >> 6, c = lin & 63;             // k-off, o-off (coalesced read)
      lt[c * 65 + r] = f2bf(W[(size_t)(tR + r) * 256 + tC + c]);
    }
    __syncthreads();
    #pragma unroll
    for (int it = 0; it < 16; ++it){
      int lin = it * 256 + tid;
      int o = lin >> 6, k = lin & 63;             // coalesced write
      Wt[(size_t)w * 65536 + (size_t)(tC + o) * 256 + tR + k] = lt[o * 65 + k];
    }
  } else {
    __shared__ int ws[4];
    int z = b - 2548, lane = tid & 63, wv = tid >> 6;
    if (tid < 250) *(int4*)&counts[z * 1000 + tid * 4] = make_int4(0, 0, 0, 0);
    int base = z * 1024 + tid * 4;
    int s = 0;
    #pragma unroll
    for (int j = 0; j < 4; ++j){
      int n0 = base + j;
      if (n0 < NN) s += (labels[n0] == 1) ? 1 : 0;
    }
    #pragma unroll
    for (int off = 32; off; off >>= 1) s += __shfl_down(s, off, 64);
    if (lane == 0) ws[wv] = s;
    __syncthreads();
    if (tid == 0) partA[z] = ws[0] + ws[1] + ws[2] + ws[3];
  }
}

// ---------------- hist + idx_emit fused ----------------
// blocks [0,1250): histogram atomics ; [1250,1270): emit idx (needs only partA)
__global__ __launch_bounds__(256) void k_hist_idx(const int* __restrict__ row,
    const int* __restrict__ labels, const int* __restrict__ partA,
    int* __restrict__ counts, int* __restrict__ idx){
  int tid = threadIdx.x;
  if (blockIdx.x < 1250){
    int e = blockIdx.x * 256 + tid;
    atomicAdd(&counts[row[e]], 1);
    return;
  }
  __shared__ int ws[4];
  __shared__ int boff_s;
  int bx = blockIdx.x - 1250;
  int lane = tid & 63, wv = tid >> 6;
  if (tid < 64){
    int v = (lane < 20) ? partA[lane] : 0;
    int acc = v;
    #pragma unroll
    for (int off = 1; off < 32; off <<= 1){
      int t = __shfl_up(acc, off, 64);
      if (lane >= off) acc += t;
    }
    if (lane == bx) boff_s = acc - v;   // exclusive prefix
  }
  int base = bx * 1024 + tid * 4;
  int c[4]; int s = 0;
  #pragma unroll
  for (int j = 0; j < 4; ++j){
    int n0 = base + j;
    c[j] = (n0 < NN && labels[n0] == 1) ? 1 : 0;
    s += c[j];
  }
  int incl = s;
  #pragma unroll
  for (int off = 1; off < 64; off <<= 1){
    int t = __shfl_up(incl, off, 64);
    if (lane >= off) incl += t;
  }
  if (lane == 63) ws[wv] = incl;
  __syncthreads();
  int woff = boff_s;
  for (int w = 0; w < wv; ++w) woff += ws[w];
  int off = woff + incl - s;
  #pragma unroll
  for (int j = 0; j < 4; ++j){
    if (c[j]){ if (off < KSEL) idx[off] = base + j; ++off; }
  }
}

// 20 blocks; each sums counts[0..base) itself, then scans its 1024-window -> start/cursor
__global__ __launch_bounds__(256) void k_row_emit(const int* __restrict__ counts,
    int* __restrict__ start, int* __restrict__ cursor){
  __shared__ int ws[4];
  __shared__ int red[4];
  int tid = threadIdx.x, lane = tid & 63, wv = tid >> 6;
  int base = blockIdx.x * 1024;
  int ps = 0;
  for (int i = tid * 4; i < base; i += 1024){
    int4 v = *(const int4*)&counts[i];
    ps += v.x + v.y + v.z + v.w;
  }
  #pragma unroll
  for (int off = 32; off; off >>= 1) ps += __shfl_down(ps, off, 64);
  if (lane == 0) red[wv] = ps;
  __syncthreads();
  int bpref = red[0] + red[1] + red[2] + red[3];
  int nb = base + tid * 4;
  int c[4]; int s = 0;
  #pragma unroll
  for (int j = 0; j < 4; ++j){
    int n0 = nb + j;
    c[j] = (n0 < NN) ? counts[n0] : 0;
    s += c[j];
  }
  int incl = s;
  #pragma unroll
  for (int off = 1; off < 64; off <<= 1){
    int t = __shfl_up(incl, off, 64);
    if (lane >= off) incl += t;
  }
  if (lane == 63) ws[wv] = incl;
  __syncthreads();
  int woff = bpref;
  for (int w = 0; w < wv; ++w) woff += ws[w];
  int run = woff + incl - s;
  #pragma unroll
  for (int j = 0; j < 4; ++j){
    int n0 = nb + j;
    if (n0 < NN){ start[n0] = run; cursor[n0] = run; run += c[j]; }
  }
  if (blockIdx.x == 0 && tid == 0) start[NN] = NE;
}

__global__ void k_scatter(const int* __restrict__ row, const int* __restrict__ col,
                          const float* __restrict__ ew, int* __restrict__ cursor,
                          int2* __restrict__ rec){
  int e = blockIdx.x * 256 + threadIdx.x;
  if (e < NE){
    int r = row[e];
    int p = atomicAdd(&cursor[r], 1);
    rec[p] = make_int2(col[e], __float_as_int(ew[e]));
  }
}

// ---------------- full SpMM: aggX = A @ Xb  (20000x256 bf16) ----------------
// one wave per row; 16B gathers, half-wave per edge (lanes 0-31: even, 32-63: odd),
// 4 gathers x 16B in flight per lane.
__global__ __launch_bounds__(256) void k_spmm_full(const unsigned short* __restrict__ Xb,
    const int* __restrict__ start, const int2* __restrict__ rec,
    unsigned short* __restrict__ aggX){
  int wave = threadIdx.x >> 6, lane = threadIdx.x & 63;
  int half = lane >> 5, hl = lane & 31;
  int n = blockIdx.x * 4 + wave;          // 5000*4 = 20000 exact
  int s = start[n], e = start[n + 1];
  int d = hl * 8;                         // dims [d, d+8)
  float acc[8] = {};
  for (int base = s; base < e; base += 64){
    int p = base + lane;
    int pc = p < e ? p : e - 1;
    int2 r = rec[pc];
    float wv = (p < e) ? __int_as_float(r.y) : 0.0f;
    int m = e - base; if (m > 64) m = 64;
    for (int j = 0; j < m; j += 8){
      int j0 = j + half, j1 = j + 2 + half, j2 = j + 4 + half, j3 = j + 6 + half;
      int   c0 = __shfl(r.x, j0), c1 = __shfl(r.x, j1);
      int   c2 = __shfl(r.x, j2), c3 = __shfl(r.x, j3);
      float w0 = __shfl(wv, j0),  w1 = __shfl(wv, j1);
      float w2 = __shfl(wv, j2),  w3 = __shfl(wv, j3);
      bf16x8 v0 = *(const bf16x8*)&Xb[(size_t)c0 * 256 + d];
      bf16x8 v1 = *(const bf16x8*)&Xb[(size_t)c1 * 256 + d];
      bf16x8 v2 = *(const bf16x8*)&Xb[(size_t)c2 * 256 + d];
      bf16x8 v3 = *(const bf16x8*)&Xb[(size_t)c3 * 256 + d];
      #pragma unroll
      for (int q = 0; q < 8; ++q){
        acc[q] += w0 * bf2f((unsigned short)v0[q]) + w1 * bf2f((unsigned short)v1[q])
                + w2 * bf2f((unsigned short)v2[q]) + w3 * bf2f((unsigned short)v3[q]);
      }
    }
  }
  #pragma unroll
  for (int q = 0; q < 8; ++q){
    float o = __shfl(acc[q], hl + 32);    // lanes<32 pull odd-half partial
    acc[q] += o;
  }
  if (half == 0){
    bf16x8 ob;
    #pragma unroll
    for (int q = 0; q < 8; ++q) ob[q] = (short)f2bf(acc[q]);
    *(bf16x8*)&aggX[(size_t)n * 256 + d] = ob;
  }
}

// ---------------- staged GEMM + bias + relu: h = relu(aggX @ W1^T + b1) ----------------
__global__ __launch_bounds__(256) void k_gemm_h(const unsigned short* __restrict__ A,
                                                const unsigned short* __restrict__ Wt,
                                                const float* __restrict__ bias,
                                                unsigned short* __restrict__ out, int M){
  __shared__ unsigned short At[128 * 64];
  __shared__ unsigned short Bt[64 * 64];
  int tid = threadIdx.x, wave = tid >> 6, lane = tid & 63;
  int lm = lane & 15, lq = lane >> 4;
  int mBase = blockIdx.x * 128;
  int oBase = blockIdx.y * 64;
  f32x4 acc[2][4] = {};
  for (int kc = 0; kc < 256; kc += 64){
    if (kc) __syncthreads();
    #pragma unroll
    for (int it = 0; it < 4; ++it){
      int s = (wave * 4 + it) * 64 + lane;
      int row = s >> 3, c = (s & 7) ^ (row & 7);
      int gr = mBase + row; if (gr >= M) gr = M - 1;
      gld_lds16(&A[(size_t)gr * 256 + kc + c * 8], &At[s * 8]);
    }
    #pragma unroll
    for (int it = 0; it < 2; ++it){
      int s = (wave * 2 + it) * 64 + lane;
      int row = s >> 3, c = (s & 7) ^ (row & 7);
      gld_lds16(&Wt[(size_t)(oBase + row) * 256 + kc + c * 8], &Bt[s * 8]);
    }
    __syncthreads();
    #pragma unroll
    for (int ks = 0; ks < 64; ks += 32){
      int cb = ks >> 3;
      int RA = wave * 32 + lm;
      int ca = ((cb + lq) ^ (RA & 7)) << 3;
      bf16x8 a0 = *(const bf16x8*)&At[RA * 64 + ca];
      bf16x8 a1 = *(const bf16x8*)&At[(RA + 16) * 64 + ca];
      #pragma unroll
      for (int os = 0; os < 4; ++os){
        int RB = os * 16 + lm;
        bf16x8 b = *(const bf16x8*)&Bt[RB * 64 + (((cb + lq) ^ (RB & 7)) << 3)];
        acc[0][os] = __builtin_amdgcn_mfma_f32_16x16x32_bf16(a0, b, acc[0][os], 0, 0, 0);
        acc[1][os] = __builtin_amdgcn_mfma_f32_16x16x32_bf16(a1, b, acc[1][os], 0, 0, 0);
      }
    }
  }
  #pragma unroll
  for (int ms = 0; ms < 2; ++ms){
    int rb = mBase + wave * 32 + ms * 16 + lq * 4;
    #pragma unroll
    for (int os = 0; os < 4; ++os){
      int col = oBase + os * 16 + lm;
      float bv = bias[col];
      #pragma unroll
      for (int r = 0; r < 4; ++r){
        int row = rb + r;
        if (row < M) out[(size_t)row * 256 + col] = f2bf(fmaxf(acc[ms][os][r] + bv, 0.f));
      }
    }
  }
}

// ---------------- selected SpMM: aggH = A[idx] @ h  (4096x256 bf16), widened ----------------
__global__ __launch_bounds__(256) void k_spmm_selH(const unsigned short* __restrict__ h,
    const int* __restrict__ idx, const int* __restrict__ start, const int2* __restrict__ rec,
    unsigned short* __restrict__ aggH){
  int wave = threadIdx.x >> 6, lane = threadIdx.x & 63;
  int half = lane >> 5, hl = lane & 31;
  int i = blockIdx.x * 4 + wave;          // 1024*4 = 4096
  int n = idx[i];
  int s = start[n], e = start[n + 1];
  int d = hl * 8;
  float acc[8] = {};
  for (int base = s; base < e; base += 64){
    int p = base + lane;
    int pc = p < e ? p : e - 1;
    int2 r = rec[pc];
    float wv = (p < e) ? __int_as_float(r.y) : 0.0f;
    int m = e - base; if (m > 64) m = 64;
    for (int j = 0; j < m; j += 8){
      int j0 = j + half, j1 = j + 2 + half, j2 = j + 4 + half, j3 = j + 6 + half;
      int   c0 = __shfl(r.x, j0), c1 = __shfl(r.x, j1);
      int   c2 = __shfl(r.x, j2), c3 = __shfl(r.x, j3);
      float w0 = __shfl(wv, j0),  w1 = __shfl(wv, j1);
      float w2 = __shfl(wv, j2),  w3 = __shfl(wv, j3);
      bf16x8 v0 = *(const bf16x8*)&h[(size_t)c0 * 256 + d];
      bf16x8 v1 = *(const bf16x8*)&h[(size_t)c1 * 256 + d];
      bf16x8 v2 = *(const bf16x8*)&h[(size_t)c2 * 256 + d];
      bf16x8 v3 = *(const bf16x8*)&h[(size_t)c3 * 256 + d];
      #pragma unroll
      for (int q = 0; q < 8; ++q){
        acc[q] += w0 * bf2f((unsigned short)v0[q]) + w1 * bf2f((unsigned short)v1[q])
                + w2 * bf2f((unsigned short)v2[q]) + w3 * bf2f((unsigned short)v3[q]);
      }
    }
  }
  #pragma unroll
  for (int q = 0; q < 8; ++q){
    float o = __shfl(acc[q], hl + 32);
    acc[q] += o;
  }
  if (half == 0){
    bf16x8 ob;
    #pragma unroll
    for (int q = 0; q < 8; ++q) ob[q] = (short)f2bf(acc[q]);
    *(bf16x8*)&aggH[(size_t)i * 256 + d] = ob;
  }
}

// ---- fused small GEMMs (z=0: out0 = aggH@W2+b2 f32 ; z=1: sel = aggX[idx]@Wsd+bsd bf16) ----
__global__ __launch_bounds__(256) void k_gemm_os(const unsigned short* __restrict__ aggH,
    const unsigned short* __restrict__ aggX, const int* __restrict__ idx,
    const unsigned short* __restrict__ Wt,
    const float* __restrict__ b2, const float* __restrict__ bsd,
    float* __restrict__ out0, unsigned short* __restrict__ sel){
  __shared__ unsigned short lds[64 * 264];
  int tid = threadIdx.x;
  int wave = tid >> 6, lane = tid & 63;
  int lm = lane & 15, lq = lane >> 4;
  int z = blockIdx.z;
  int mBase = blockIdx.x * 128;
  int oBase = blockIdx.y * 64;
  const unsigned short* Wt2 = Wt + (z ? 256 * 256 : 512 * 256);
  const float* bias = z ? bsd : b2;
  #pragma unroll
  for (int it = 0; it < 8; ++it){
    int c = it * 256 + tid;
    int o = c >> 5, kk = (c & 31) << 3;
    *(bf16x8*)&lds[o * 264 + kk] = *(const bf16x8*)&Wt2[(oBase + o) * 256 + kk];
  }
  __syncthreads();
  int r0 = mBase + wave * 32 + lm;
  const unsigned short* A0;
  const unsigned short* A1;
  if (z){
    A0 = aggX + (size_t)idx[r0] * 256;
    A1 = aggX + (size_t)idx[r0 + 16] * 256;
  } else {
    A0 = aggH + (size_t)r0 * 256;
    A1 = aggH + (size_t)(r0 + 16) * 256;
  }
  f32x4 acc[2][4] = {};
  #pragma unroll
  for (int ks = 0; ks < 256; ks += 32){
    int ka = ks + lq * 8;
    bf16x8 a0 = *(const bf16x8*)&A0[ka];
    bf16x8 a1 = *(const bf16x8*)&A1[ka];
    #pragma unroll
    for (int os = 0; os < 4; ++os){
      bf16x8 b = *(const bf16x8*)&lds[(os * 16 + lm) * 264 + ka];
      acc[0][os] = __builtin_amdgcn_mfma_f32_16x16x32_bf16(a0, b, acc[0][os], 0, 0, 0);
      acc[1][os] = __builtin_amdgcn_mfma_f32_16x16x32_bf16(a1, b, acc[1][os], 0, 0, 0);
    }
  }
  #pragma unroll
  for (int ms = 0; ms < 2; ++ms){
    int rb = mBase + wave * 32 + ms * 16 + lq * 4;
    #pragma unroll
    for (int os = 0; os < 4; ++os){
      int col = oBase + os * 16 + lm;
      float bv = bias[col];
      #pragma unroll
      for (int r = 0; r < 4; ++r){
        float v = acc[ms][os][r] + bv;
        if (z) sel[(size_t)(rb + r) * 256 + col] = f2bf(v);
        else   out0[(size_t)(rb + r) * 256 + col] = v;
      }
    }
  }
}

// ---------------- s @ s^T staged: [4096,256] bf16 -> [4096,4096] f32 ----------------
__global__ __launch_bounds__(256) void k_gemm_st(const unsigned short* __restrict__ S,
                                                 float* __restrict__ out1){
  __shared__ unsigned short At[128 * 64];
  __shared__ unsigned short Bt[128 * 64];
  int tid = threadIdx.x, wave = tid >> 6, lane = tid & 63;
  int lm = lane & 15, lq = lane >> 4;
  int mBase = blockIdx.x * 128;
  int oBase = blockIdx.y * 128;
  f32x4 acc[2][8] = {};
  for (int kc = 0; kc < 256; kc += 64){
    if (kc) __syncthreads();
    #pragma unroll
    for (int it = 0; it < 4; ++it){
      int s = (wave * 4 + it) * 64 + lane;
      int row = s >> 3, c = (s & 7) ^ (row & 7);
      gld_lds16(&S[(size_t)(mBase + row) * 256 + kc + c * 8], &At[s * 8]);
      gld_lds16(&S[(size_t)(oBase + row) * 256 + kc + c * 8], &Bt[s * 8]);
    }
    __syncthreads();
    #pragma unroll
    for (int ks = 0; ks < 64; ks += 32){
      int cb = ks >> 3;
      int RA = wave * 32 + lm;
      int ca = ((cb + lq) ^ (RA & 7)) << 3;
      bf16x8 a0 = *(const bf16x8*)&At[RA * 64 + ca];
      bf16x8 a1 = *(const bf16x8*)&At[(RA + 16) * 64 + ca];
      #pragma unroll
      for (int os = 0; os < 8; ++os){
        int RB = os * 16 + lm;
        bf16x8 b = *(const bf16x8*)&Bt[RB * 64 + (((cb + lq) ^ (RB & 7)) << 3)];
        acc[0][os] = __builtin_amdgcn_mfma_f32_16x16x32_bf16(a0, b, acc[0][os], 0, 0, 0);
        acc[1][os] = __builtin_amdgcn_mfma_f32_16x16x32_bf16(a1, b, acc[1][os], 0, 0, 0);
      }
    }
  }
  #pragma unroll
  for (int ms = 0; ms < 2; ++ms){
    int rb = mBase + wave * 32 + ms * 16 + lq * 4;
    #pragma unroll
    for (int os = 0; os < 8; ++os){
      int col = oBase + os * 16 + lm;
      #pragma unroll
      for (int r = 0; r < 4; ++r)
        out1[(size_t)(rb + r) * 4096 + col] = acc[ms][os][r];
    }
  }
}

extern "C" void kernel_launch(void* const* d_in, const int* in_sizes, int n_in,
                              void* d_out, int out_size, void* d_ws, size_t ws_size,
                              hipStream_t stream){
  const float* X    = (const float*)d_in[0];
  const int*   erow = (const int*)d_in[1];
  const int*   ecol = (const int*)d_in[2];
  const float* ew   = (const float*)d_in[3];
  const int*   labels = (const int*)d_in[4];
  const float* W1   = (const float*)d_in[5];
  const float* b1   = (const float*)d_in[6];
  const float* W2   = (const float*)d_in[7];
  const float* b2   = (const float*)d_in[8];
  const float* Wsd  = (const float*)d_in[9];
  const float* bsd  = (const float*)d_in[10];
  float* out0 = (float*)d_out;
  float* out1 = out0 + (size_t)KSEL * 256;

  char* ws = (char*)d_ws;
  unsigned short* Xb   = (unsigned short*)(ws);               // 10,240,000
  unsigned short* Wt   = (unsigned short*)(ws + 10240000);    //    393,216
  unsigned short* aggX = (unsigned short*)(ws + 10633216);    // 10,240,000
  unsigned short* h    = (unsigned short*)(ws + 20873216);    // 10,240,000
  unsigned short* aggH = (unsigned short*)(ws + 31113216);    //  2,097,152
  unsigned short* sel  = (unsigned short*)(ws + 33210368);    //  2,097,152
  int* idx    = (int*)(ws + 35307520);                        //     16,384
  int* counts = (int*)(ws + 35323904);                        //     80,000
  int* startp = (int*)(ws + 35403904);                        //     80,004
  int* cursor = (int*)(ws + 35483908);                        //     80,000
  int2* rec   = (int2*)(ws + 35563912);                       //  2,560,000
  int* partA  = (int*)(ws + 38123912);                        //        128

  k_prep<<<2568, 256, 0, stream>>>(X, W1, Wsd, W2, labels, Xb, Wt, counts, partA);
  k_hist_idx<<<1270, 256, 0, stream>>>(erow, labels, partA, counts, idx);
  k_row_emit<<<20, 256, 0, stream>>>(counts, startp, cursor);
  k_scatter<<<NE / 256, 256, 0, stream>>>(erow, ecol, ew, cursor, rec);
  k_spmm_full<<<5000, 256, 0, stream>>>(Xb, startp, rec, aggX);
  k_gemm_h<<<dim3(157, 4), 256, 0, stream>>>(aggX, Wt, b1, h, NN);
  k_spmm_selH<<<1024, 256, 0, stream>>>(h, idx, startp, rec, aggH);
  k_gemm_os<<<dim3(32, 4, 2), 256, 0, stream>>>(aggH, aggX, idx, Wt, b2, bsd, out0, sel);
  k_gemm_st<<<dim3(32, 32), 256, 0, stream>>>(sel, out1);
}